// Round 3
// baseline (1365.910 us; speedup 1.0000x reference)
//
#include <hip/hip_runtime.h>

#define DF 128   // feature dim (both layers)

__device__ __forceinline__ float4 f4zero() { return make_float4(0.f, 0.f, 0.f, 0.f); }

// out = act(x @ W + b). MODE 0: plain (no bias, no act). MODE 1: bias + relu.
// x: [nrows, 128], W: [128,128] row-major (W[k][c]), out: [nrows,128].
// Block: 256 threads. Each block: 128 rows. Thread (r=tid&63, q=tid>>6):
// rows {r, r+64}, cols [32q, 32q+32). W broadcast from LDS (wave-uniform float4 reads).
template<int MODE>
__global__ __launch_bounds__(256) void gemm128(const float* __restrict__ x,
                                               const float* __restrict__ W,
                                               const float* __restrict__ b,
                                               float* __restrict__ out, int nrows)
{
    __shared__ float Ws[DF * DF];
    __shared__ float bs[DF];
    const int tid = threadIdx.x;
    {
        const float4* Wv = (const float4*)W;
        float4* Wsv = (float4*)Ws;
        #pragma unroll 4
        for (int i = tid; i < DF * DF / 4; i += 256) Wsv[i] = Wv[i];
        if (MODE == 1 && tid < DF / 4) ((float4*)bs)[tid] = ((const float4*)b)[tid];
    }
    __syncthreads();

    const int r = tid & 63;
    const int q = tid >> 6;
    const int row0 = blockIdx.x * 128 + r;
    const int row1 = row0 + 64;
    const int rl0 = min(row0, nrows - 1);
    const int rl1 = min(row1, nrows - 1);
    const float4* xp0 = (const float4*)(x + (size_t)rl0 * DF);
    const float4* xp1 = (const float4*)(x + (size_t)rl1 * DF);

    float4 acc0[8], acc1[8];
    #pragma unroll
    for (int j = 0; j < 8; ++j) { acc0[j] = f4zero(); acc1[j] = f4zero(); }

    #pragma unroll 4
    for (int k0 = 0; k0 < DF; k0 += 4) {
        float4 xa = xp0[k0 >> 2];
        float4 xb = xp1[k0 >> 2];
        const float ax[4] = {xa.x, xa.y, xa.z, xa.w};
        const float bx[4] = {xb.x, xb.y, xb.z, xb.w};
        #pragma unroll
        for (int dk = 0; dk < 4; ++dk) {
            const float4* wr = (const float4*)&Ws[(k0 + dk) * DF + (q << 5)];
            #pragma unroll
            for (int j = 0; j < 8; ++j) {
                float4 w = wr[j];
                acc0[j].x = fmaf(ax[dk], w.x, acc0[j].x);
                acc0[j].y = fmaf(ax[dk], w.y, acc0[j].y);
                acc0[j].z = fmaf(ax[dk], w.z, acc0[j].z);
                acc0[j].w = fmaf(ax[dk], w.w, acc0[j].w);
                acc1[j].x = fmaf(bx[dk], w.x, acc1[j].x);
                acc1[j].y = fmaf(bx[dk], w.y, acc1[j].y);
                acc1[j].z = fmaf(bx[dk], w.z, acc1[j].z);
                acc1[j].w = fmaf(bx[dk], w.w, acc1[j].w);
            }
        }
    }

    if (row0 < nrows) {
        float4* o = (float4*)(out + (size_t)row0 * DF + (q << 5));
        #pragma unroll
        for (int j = 0; j < 8; ++j) {
            float4 t = acc0[j];
            if (MODE == 1) {
                const int c = (q << 5) + 4 * j;
                t.x = fmaxf(t.x + bs[c + 0], 0.f);
                t.y = fmaxf(t.y + bs[c + 1], 0.f);
                t.z = fmaxf(t.z + bs[c + 2], 0.f);
                t.w = fmaxf(t.w + bs[c + 3], 0.f);
            }
            o[j] = t;
        }
    }
    if (row1 < nrows) {
        float4* o = (float4*)(out + (size_t)row1 * DF + (q << 5));
        #pragma unroll
        for (int j = 0; j < 8; ++j) {
            float4 t = acc1[j];
            if (MODE == 1) {
                const int c = (q << 5) + 4 * j;
                t.x = fmaxf(t.x + bs[c + 0], 0.f);
                t.y = fmaxf(t.y + bs[c + 1], 0.f);
                t.z = fmaxf(t.z + bs[c + 2], 0.f);
                t.w = fmaxf(t.w + bs[c + 3], 0.f);
            }
            o[j] = t;
        }
    }
}

// out = relu(LN(neigh @ Wneigh + xs + bias) * gamma + beta)
__global__ __launch_bounds__(256) void gemm_ln(const float* __restrict__ neigh,
                                               const float* __restrict__ W,
                                               const float* __restrict__ xs,
                                               const float* __restrict__ bias,
                                               const float* __restrict__ gamma,
                                               const float* __restrict__ beta,
                                               float* __restrict__ out, int nrows)
{
    __shared__ float Ws[DF * DF];
    __shared__ float bs[DF], gs[DF], bts[DF];
    __shared__ float redS[4][DF], redQ[4][DF];
    const int tid = threadIdx.x;
    {
        const float4* Wv = (const float4*)W;
        float4* Wsv = (float4*)Ws;
        #pragma unroll 4
        for (int i = tid; i < DF * DF / 4; i += 256) Wsv[i] = Wv[i];
        if (tid < DF / 4) {
            ((float4*)bs)[tid]  = ((const float4*)bias)[tid];
            ((float4*)gs)[tid]  = ((const float4*)gamma)[tid];
            ((float4*)bts)[tid] = ((const float4*)beta)[tid];
        }
    }
    __syncthreads();

    const int r = tid & 63;
    const int q = tid >> 6;
    const int row0 = blockIdx.x * 128 + r;
    const int row1 = row0 + 64;
    const int rl0 = min(row0, nrows - 1);
    const int rl1 = min(row1, nrows - 1);
    const float4* xp0 = (const float4*)(neigh + (size_t)rl0 * DF);
    const float4* xp1 = (const float4*)(neigh + (size_t)rl1 * DF);

    float4 acc0[8], acc1[8];
    #pragma unroll
    for (int j = 0; j < 8; ++j) { acc0[j] = f4zero(); acc1[j] = f4zero(); }

    #pragma unroll 4
    for (int k0 = 0; k0 < DF; k0 += 4) {
        float4 xa = xp0[k0 >> 2];
        float4 xb = xp1[k0 >> 2];
        const float ax[4] = {xa.x, xa.y, xa.z, xa.w};
        const float bx[4] = {xb.x, xb.y, xb.z, xb.w};
        #pragma unroll
        for (int dk = 0; dk < 4; ++dk) {
            const float4* wr = (const float4*)&Ws[(k0 + dk) * DF + (q << 5)];
            #pragma unroll
            for (int j = 0; j < 8; ++j) {
                float4 w = wr[j];
                acc0[j].x = fmaf(ax[dk], w.x, acc0[j].x);
                acc0[j].y = fmaf(ax[dk], w.y, acc0[j].y);
                acc0[j].z = fmaf(ax[dk], w.z, acc0[j].z);
                acc0[j].w = fmaf(ax[dk], w.w, acc0[j].w);
                acc1[j].x = fmaf(bx[dk], w.x, acc1[j].x);
                acc1[j].y = fmaf(bx[dk], w.y, acc1[j].y);
                acc1[j].z = fmaf(bx[dk], w.z, acc1[j].z);
                acc1[j].w = fmaf(bx[dk], w.w, acc1[j].w);
            }
        }
    }

    // add xs + bias, accumulate row stats
    const float4* xsp0 = (const float4*)(xs + (size_t)rl0 * DF + (q << 5));
    const float4* xsp1 = (const float4*)(xs + (size_t)rl1 * DF + (q << 5));
    float s1a = 0.f, s2a = 0.f, s1b = 0.f, s2b = 0.f;
    #pragma unroll
    for (int j = 0; j < 8; ++j) {
        const int c = (q << 5) + 4 * j;
        float4 xv = xsp0[j];
        float4 t = acc0[j];
        t.x += xv.x + bs[c + 0]; t.y += xv.y + bs[c + 1];
        t.z += xv.z + bs[c + 2]; t.w += xv.w + bs[c + 3];
        acc0[j] = t;
        s1a += t.x + t.y + t.z + t.w;
        s2a += t.x * t.x + t.y * t.y + t.z * t.z + t.w * t.w;
        float4 yv = xsp1[j];
        float4 u = acc1[j];
        u.x += yv.x + bs[c + 0]; u.y += yv.y + bs[c + 1];
        u.z += yv.z + bs[c + 2]; u.w += yv.w + bs[c + 3];
        acc1[j] = u;
        s1b += u.x + u.y + u.z + u.w;
        s2b += u.x * u.x + u.y * u.y + u.z * u.z + u.w * u.w;
    }
    redS[q][r] = s1a; redQ[q][r] = s2a;
    redS[q][r + 64] = s1b; redQ[q][r + 64] = s2b;
    __syncthreads();

    const float mu0  = (redS[0][r] + redS[1][r] + redS[2][r] + redS[3][r]) * (1.f / 128.f);
    const float ex20 = (redQ[0][r] + redQ[1][r] + redQ[2][r] + redQ[3][r]) * (1.f / 128.f);
    const float inv0 = rsqrtf(ex20 - mu0 * mu0 + 1e-5f);
    const float mu1  = (redS[0][r+64] + redS[1][r+64] + redS[2][r+64] + redS[3][r+64]) * (1.f / 128.f);
    const float ex21 = (redQ[0][r+64] + redQ[1][r+64] + redQ[2][r+64] + redQ[3][r+64]) * (1.f / 128.f);
    const float inv1 = rsqrtf(ex21 - mu1 * mu1 + 1e-5f);

    if (row0 < nrows) {
        float4* o = (float4*)(out + (size_t)row0 * DF + (q << 5));
        #pragma unroll
        for (int j = 0; j < 8; ++j) {
            const int c = (q << 5) + 4 * j;
            float4 t = acc0[j];
            t.x = fmaxf((t.x - mu0) * inv0 * gs[c + 0] + bts[c + 0], 0.f);
            t.y = fmaxf((t.y - mu0) * inv0 * gs[c + 1] + bts[c + 1], 0.f);
            t.z = fmaxf((t.z - mu0) * inv0 * gs[c + 2] + bts[c + 2], 0.f);
            t.w = fmaxf((t.w - mu0) * inv0 * gs[c + 3] + bts[c + 3], 0.f);
            o[j] = t;
        }
    }
    if (row1 < nrows) {
        float4* o = (float4*)(out + (size_t)row1 * DF + (q << 5));
        #pragma unroll
        for (int j = 0; j < 8; ++j) {
            const int c = (q << 5) + 4 * j;
            float4 t = acc1[j];
            t.x = fmaxf((t.x - mu1) * inv1 * gs[c + 0] + bts[c + 0], 0.f);
            t.y = fmaxf((t.y - mu1) * inv1 * gs[c + 1] + bts[c + 1], 0.f);
            t.z = fmaxf((t.z - mu1) * inv1 * gs[c + 2] + bts[c + 2], 0.f);
            t.w = fmaxf((t.w - mu1) * inv1 * gs[c + 3] + bts[c + 3], 0.f);
            o[j] = t;
        }
    }
}

// neigh[dst] = max(neigh[dst], h[src]) elementwise. h >= 0 (post-relu), neigh
// zero-initialized, so uint atomicMax on the float bit pattern is exact and
// zero-valued messages can be skipped. One wave per edge, float2 per lane.
__global__ __launch_bounds__(256) void edge_max(const float* __restrict__ h,
                                                const int* __restrict__ src,
                                                const int* __restrict__ dst,
                                                unsigned int* __restrict__ neigh, int nE)
{
    const int lane = threadIdx.x & 63;
    const int wid = threadIdx.x >> 6;
    const int stride = gridDim.x * 4;
    for (int e = blockIdx.x * 4 + wid; e < nE; e += stride) {
        const int s = src[e];
        const int d = dst[e];
        const float2 hv = ((const float2*)(h + (size_t)s * DF))[lane];
        unsigned int* o = neigh + (size_t)d * DF + lane * 2;
        if (hv.x > 0.f) atomicMax(o,     __float_as_uint(hv.x));
        if (hv.y > 0.f) atomicMax(o + 1, __float_as_uint(hv.y));
    }
}

// column-wise max over all rows (values >= 0, g zero-initialized)
__global__ __launch_bounds__(128) void colmax(const float* __restrict__ x,
                                              unsigned int* __restrict__ g, int nrows)
{
    const int c = threadIdx.x;
    float m = 0.f;
    for (int n = blockIdx.x; n < nrows; n += gridDim.x)
        m = fmaxf(m, x[(size_t)n * DF + c]);
    atomicMax(g + c, __float_as_uint(m));
}

// out = (g @ Wfc1 + bfc1) @ Wfc + bfc   (single block, 128 threads)
__global__ __launch_bounds__(128) void head(const float* __restrict__ g,
                                            const float* __restrict__ Wfc1,
                                            const float* __restrict__ bfc1,
                                            const float* __restrict__ Wfc,
                                            const float* __restrict__ bfc,
                                            float* __restrict__ out)
{
    __shared__ float gsh[DF];
    __shared__ float tsh[DF];
    const int t = threadIdx.x;
    gsh[t] = g[t];
    __syncthreads();
    float acc = bfc1[t];
    #pragma unroll 8
    for (int k = 0; k < DF; ++k) acc = fmaf(gsh[k], Wfc1[k * DF + t], acc);
    tsh[t] = acc * Wfc[t];
    __syncthreads();
    if (t == 0) {
        float s = 0.f;
        for (int i = 0; i < DF; ++i) s += tsh[i];
        out[0] = s + bfc[0];
    }
}

extern "C" void kernel_launch(void* const* d_in, const int* in_sizes, int n_in,
                              void* d_out, int out_size, void* d_ws, size_t ws_size,
                              hipStream_t stream) {
    const float* x0     = (const float*)d_in[0];
    const int*   src    = (const int*)d_in[1];
    const int*   dst    = (const int*)d_in[2];
    const float* Wpool0 = (const float*)d_in[3];
    const float* bpool0 = (const float*)d_in[4];
    const float* Wself0 = (const float*)d_in[5];
    const float* Wneigh0= (const float*)d_in[6];
    const float* bias0  = (const float*)d_in[7];
    const float* gamma0 = (const float*)d_in[8];
    const float* beta0  = (const float*)d_in[9];
    const float* Wpool1 = (const float*)d_in[10];
    const float* bpool1 = (const float*)d_in[11];
    const float* Wself1 = (const float*)d_in[12];
    const float* Wneigh1= (const float*)d_in[13];
    const float* bias1  = (const float*)d_in[14];
    const float* gamma1 = (const float*)d_in[15];
    const float* beta1  = (const float*)d_in[16];
    const float* Wfc1   = (const float*)d_in[17];
    const float* bfc1   = (const float*)d_in[18];
    const float* Wfc    = (const float*)d_in[19];
    const float* bfc    = (const float*)d_in[20];

    const int N  = in_sizes[0] / DF;   // 50000
    const int nE = in_sizes[1];        // 800000
    const size_t bufElems = (size_t)N * DF;

    float* A = (float*)d_ws;                 // 25.6 MB each
    float* B = A + bufElems;
    float* C = B + bufElems;
    unsigned int* g = (unsigned int*)(C + bufElems);

    const dim3 gG((N + 127) / 128), bG(256);

    // ---- layer 0 ----
    gemm128<1><<<gG, bG, 0, stream>>>(x0, Wpool0, bpool0, A, N);     // A = h0 = relu(x0@Wpool0+b)
    gemm128<0><<<gG, bG, 0, stream>>>(x0, Wself0, nullptr, B, N);    // B = x0@Wself0
    hipMemsetAsync(C, 0, bufElems * sizeof(float), stream);
    edge_max<<<4096, 256, 0, stream>>>(A, src, dst, (unsigned int*)C, nE);  // C = neigh0
    gemm_ln<<<gG, bG, 0, stream>>>(C, Wneigh0, B, bias0, gamma0, beta0, A, N); // A = x1

    // ---- layer 1 ----
    gemm128<1><<<gG, bG, 0, stream>>>(A, Wpool1, bpool1, B, N);      // B = h1
    gemm128<0><<<gG, bG, 0, stream>>>(A, Wself1, nullptr, C, N);     // C = x1@Wself1
    hipMemsetAsync(A, 0, bufElems * sizeof(float), stream);
    edge_max<<<4096, 256, 0, stream>>>(B, src, dst, (unsigned int*)A, nE);  // A = neigh1
    gemm_ln<<<gG, bG, 0, stream>>>(A, Wneigh1, C, bias1, gamma1, beta1, B, N); // B = x2

    // ---- readout ----
    hipMemsetAsync(g, 0, DF * sizeof(float), stream);
    colmax<<<512, 128, 0, stream>>>(B, g, N);
    head<<<1, 128, 0, stream>>>((const float*)g, Wfc1, bfc1, Wfc, bfc, (float*)d_out);
}

// Round 7
// 622.777 us; speedup vs baseline: 2.1933x; 2.1933x over previous
//
#include <hip/hip_runtime.h>

#define DF 128   // feature dim (both layers)

__device__ __forceinline__ float4 f4zero() { return make_float4(0.f, 0.f, 0.f, 0.f); }

// ---------------- GEMM kernels (unchanged from baseline) ----------------

// out = act(x @ W + b). MODE 0: plain. MODE 1: bias + relu.
template<int MODE>
__global__ __launch_bounds__(256) void gemm128(const float* __restrict__ x,
                                               const float* __restrict__ W,
                                               const float* __restrict__ b,
                                               float* __restrict__ out, int nrows)
{
    __shared__ float Ws[DF * DF];
    __shared__ float bs[DF];
    const int tid = threadIdx.x;
    {
        const float4* Wv = (const float4*)W;
        float4* Wsv = (float4*)Ws;
        #pragma unroll 4
        for (int i = tid; i < DF * DF / 4; i += 256) Wsv[i] = Wv[i];
        if (MODE == 1 && tid < DF / 4) ((float4*)bs)[tid] = ((const float4*)b)[tid];
    }
    __syncthreads();

    const int r = tid & 63;
    const int q = tid >> 6;
    const int row0 = blockIdx.x * 128 + r;
    const int row1 = row0 + 64;
    const int rl0 = min(row0, nrows - 1);
    const int rl1 = min(row1, nrows - 1);
    const float4* xp0 = (const float4*)(x + (size_t)rl0 * DF);
    const float4* xp1 = (const float4*)(x + (size_t)rl1 * DF);

    float4 acc0[8], acc1[8];
    #pragma unroll
    for (int j = 0; j < 8; ++j) { acc0[j] = f4zero(); acc1[j] = f4zero(); }

    #pragma unroll 4
    for (int k0 = 0; k0 < DF; k0 += 4) {
        float4 xa = xp0[k0 >> 2];
        float4 xb = xp1[k0 >> 2];
        const float ax[4] = {xa.x, xa.y, xa.z, xa.w};
        const float bx[4] = {xb.x, xb.y, xb.z, xb.w};
        #pragma unroll
        for (int dk = 0; dk < 4; ++dk) {
            const float4* wr = (const float4*)&Ws[(k0 + dk) * DF + (q << 5)];
            #pragma unroll
            for (int j = 0; j < 8; ++j) {
                float4 w = wr[j];
                acc0[j].x = fmaf(ax[dk], w.x, acc0[j].x);
                acc0[j].y = fmaf(ax[dk], w.y, acc0[j].y);
                acc0[j].z = fmaf(ax[dk], w.z, acc0[j].z);
                acc0[j].w = fmaf(ax[dk], w.w, acc0[j].w);
                acc1[j].x = fmaf(bx[dk], w.x, acc1[j].x);
                acc1[j].y = fmaf(bx[dk], w.y, acc1[j].y);
                acc1[j].z = fmaf(bx[dk], w.z, acc1[j].z);
                acc1[j].w = fmaf(bx[dk], w.w, acc1[j].w);
            }
        }
    }

    if (row0 < nrows) {
        float4* o = (float4*)(out + (size_t)row0 * DF + (q << 5));
        #pragma unroll
        for (int j = 0; j < 8; ++j) {
            float4 t = acc0[j];
            if (MODE == 1) {
                const int c = (q << 5) + 4 * j;
                t.x = fmaxf(t.x + bs[c + 0], 0.f);
                t.y = fmaxf(t.y + bs[c + 1], 0.f);
                t.z = fmaxf(t.z + bs[c + 2], 0.f);
                t.w = fmaxf(t.w + bs[c + 3], 0.f);
            }
            o[j] = t;
        }
    }
    if (row1 < nrows) {
        float4* o = (float4*)(out + (size_t)row1 * DF + (q << 5));
        #pragma unroll
        for (int j = 0; j < 8; ++j) {
            float4 t = acc1[j];
            if (MODE == 1) {
                const int c = (q << 5) + 4 * j;
                t.x = fmaxf(t.x + bs[c + 0], 0.f);
                t.y = fmaxf(t.y + bs[c + 1], 0.f);
                t.z = fmaxf(t.z + bs[c + 2], 0.f);
                t.w = fmaxf(t.w + bs[c + 3], 0.f);
            }
            o[j] = t;
        }
    }
}

// out = relu(LN(neigh @ Wneigh + xs + bias) * gamma + beta)
__global__ __launch_bounds__(256) void gemm_ln(const float* __restrict__ neigh,
                                               const float* __restrict__ W,
                                               const float* __restrict__ xs,
                                               const float* __restrict__ bias,
                                               const float* __restrict__ gamma,
                                               const float* __restrict__ beta,
                                               float* __restrict__ out, int nrows)
{
    __shared__ float Ws[DF * DF];
    __shared__ float bs[DF], gs[DF], bts[DF];
    __shared__ float redS[4][DF], redQ[4][DF];
    const int tid = threadIdx.x;
    {
        const float4* Wv = (const float4*)W;
        float4* Wsv = (float4*)Ws;
        #pragma unroll 4
        for (int i = tid; i < DF * DF / 4; i += 256) Wsv[i] = Wv[i];
        if (tid < DF / 4) {
            ((float4*)bs)[tid]  = ((const float4*)bias)[tid];
            ((float4*)gs)[tid]  = ((const float4*)gamma)[tid];
            ((float4*)bts)[tid] = ((const float4*)beta)[tid];
        }
    }
    __syncthreads();

    const int r = tid & 63;
    const int q = tid >> 6;
    const int row0 = blockIdx.x * 128 + r;
    const int row1 = row0 + 64;
    const int rl0 = min(row0, nrows - 1);
    const int rl1 = min(row1, nrows - 1);
    const float4* xp0 = (const float4*)(neigh + (size_t)rl0 * DF);
    const float4* xp1 = (const float4*)(neigh + (size_t)rl1 * DF);

    float4 acc0[8], acc1[8];
    #pragma unroll
    for (int j = 0; j < 8; ++j) { acc0[j] = f4zero(); acc1[j] = f4zero(); }

    #pragma unroll 4
    for (int k0 = 0; k0 < DF; k0 += 4) {
        float4 xa = xp0[k0 >> 2];
        float4 xb = xp1[k0 >> 2];
        const float ax[4] = {xa.x, xa.y, xa.z, xa.w};
        const float bx[4] = {xb.x, xb.y, xb.z, xb.w};
        #pragma unroll
        for (int dk = 0; dk < 4; ++dk) {
            const float4* wr = (const float4*)&Ws[(k0 + dk) * DF + (q << 5)];
            #pragma unroll
            for (int j = 0; j < 8; ++j) {
                float4 w = wr[j];
                acc0[j].x = fmaf(ax[dk], w.x, acc0[j].x);
                acc0[j].y = fmaf(ax[dk], w.y, acc0[j].y);
                acc0[j].z = fmaf(ax[dk], w.z, acc0[j].z);
                acc0[j].w = fmaf(ax[dk], w.w, acc0[j].w);
                acc1[j].x = fmaf(bx[dk], w.x, acc1[j].x);
                acc1[j].y = fmaf(bx[dk], w.y, acc1[j].y);
                acc1[j].z = fmaf(bx[dk], w.z, acc1[j].z);
                acc1[j].w = fmaf(bx[dk], w.w, acc1[j].w);
            }
        }
    }

    const float4* xsp0 = (const float4*)(xs + (size_t)rl0 * DF + (q << 5));
    const float4* xsp1 = (const float4*)(xs + (size_t)rl1 * DF + (q << 5));
    float s1a = 0.f, s2a = 0.f, s1b = 0.f, s2b = 0.f;
    #pragma unroll
    for (int j = 0; j < 8; ++j) {
        const int c = (q << 5) + 4 * j;
        float4 xv = xsp0[j];
        float4 t = acc0[j];
        t.x += xv.x + bs[c + 0]; t.y += xv.y + bs[c + 1];
        t.z += xv.z + bs[c + 2]; t.w += xv.w + bs[c + 3];
        acc0[j] = t;
        s1a += t.x + t.y + t.z + t.w;
        s2a += t.x * t.x + t.y * t.y + t.z * t.z + t.w * t.w;
        float4 yv = xsp1[j];
        float4 u = acc1[j];
        u.x += yv.x + bs[c + 0]; u.y += yv.y + bs[c + 1];
        u.z += yv.z + bs[c + 2]; u.w += yv.w + bs[c + 3];
        acc1[j] = u;
        s1b += u.x + u.y + u.z + u.w;
        s2b += u.x * u.x + u.y * u.y + u.z * u.z + u.w * u.w;
    }
    redS[q][r] = s1a; redQ[q][r] = s2a;
    redS[q][r + 64] = s1b; redQ[q][r + 64] = s2b;
    __syncthreads();

    const float mu0  = (redS[0][r] + redS[1][r] + redS[2][r] + redS[3][r]) * (1.f / 128.f);
    const float ex20 = (redQ[0][r] + redQ[1][r] + redQ[2][r] + redQ[3][r]) * (1.f / 128.f);
    const float inv0 = rsqrtf(ex20 - mu0 * mu0 + 1e-5f);
    const float mu1  = (redS[0][r+64] + redS[1][r+64] + redS[2][r+64] + redS[3][r+64]) * (1.f / 128.f);
    const float ex21 = (redQ[0][r+64] + redQ[1][r+64] + redQ[2][r+64] + redQ[3][r+64]) * (1.f / 128.f);
    const float inv1 = rsqrtf(ex21 - mu1 * mu1 + 1e-5f);

    if (row0 < nrows) {
        float4* o = (float4*)(out + (size_t)row0 * DF + (q << 5));
        #pragma unroll
        for (int j = 0; j < 8; ++j) {
            const int c = (q << 5) + 4 * j;
            float4 t = acc0[j];
            t.x = fmaxf((t.x - mu0) * inv0 * gs[c + 0] + bts[c + 0], 0.f);
            t.y = fmaxf((t.y - mu0) * inv0 * gs[c + 1] + bts[c + 1], 0.f);
            t.z = fmaxf((t.z - mu0) * inv0 * gs[c + 2] + bts[c + 2], 0.f);
            t.w = fmaxf((t.w - mu0) * inv0 * gs[c + 3] + bts[c + 3], 0.f);
            o[j] = t;
        }
    }
    if (row1 < nrows) {
        float4* o = (float4*)(out + (size_t)row1 * DF + (q << 5));
        #pragma unroll
        for (int j = 0; j < 8; ++j) {
            const int c = (q << 5) + 4 * j;
            float4 t = acc1[j];
            t.x = fmaxf((t.x - mu1) * inv1 * gs[c + 0] + bts[c + 0], 0.f);
            t.y = fmaxf((t.y - mu1) * inv1 * gs[c + 1] + bts[c + 1], 0.f);
            t.z = fmaxf((t.z - mu1) * inv1 * gs[c + 2] + bts[c + 2], 0.f);
            t.w = fmaxf((t.w - mu1) * inv1 * gs[c + 3] + bts[c + 3], 0.f);
            o[j] = t;
        }
    }
}

// ---------------- CSR build (counting sort by dst; built once, used twice) ----------------

__global__ __launch_bounds__(256) void hist_deg(const int* __restrict__ dst,
                                                int* __restrict__ deg, int nE)
{
    const int e = blockIdx.x * 256 + threadIdx.x;
    if (e < nE) atomicAdd(&deg[dst[e]], 1);
}

// single-block exclusive scan of deg[0..n) -> start[0..n] (start[n]=total), cursor copy
__global__ __launch_bounds__(1024) void scan_deg(const int* __restrict__ deg,
                                                 int* __restrict__ start,
                                                 int* __restrict__ cursor, int n)
{
    __shared__ int sums[1024];
    const int t = threadIdx.x;
    const int chunk = (n + 1023) / 1024;
    const int lo = t * chunk;
    const int hi = min(lo + chunk, n);
    int s = 0;
    for (int i = lo; i < hi; ++i) s += deg[i];
    sums[t] = s;
    __syncthreads();
    // Hillis-Steele inclusive scan over 1024 partials
    for (int off = 1; off < 1024; off <<= 1) {
        int tmp = (t >= off) ? sums[t - off] : 0;
        __syncthreads();
        sums[t] += tmp;
        __syncthreads();
    }
    int run = sums[t] - s;   // exclusive prefix of this thread's chunk
    for (int i = lo; i < hi; ++i) {
        start[i] = run;
        cursor[i] = run;
        run += deg[i];
    }
    if (t == 1023) start[n] = sums[1023];
}

__global__ __launch_bounds__(256) void scatter_edges(const int* __restrict__ src,
                                                     const int* __restrict__ dst,
                                                     int* __restrict__ cursor,
                                                     int* __restrict__ csr_src, int nE)
{
    const int e = blockIdx.x * 256 + threadIdx.x;
    if (e < nE) {
        const int p = atomicAdd(&cursor[dst[e]], 1);
        csr_src[p] = src[e];   // order within a node is arbitrary; max is commutative
    }
}

// ---------------- pull-based segment max: neigh[n] = max over in-edges of h[src] ----------------
// One wave per node; float2 per lane covers the 512B row coalesced. Srcs preloaded
// 64-at-a-time coalesced, then broadcast via shfl. Deg-0 nodes write zeros (DGL semantics).
__global__ __launch_bounds__(256) void pull_max(const float* __restrict__ h,
                                                const int* __restrict__ csr_src,
                                                const int* __restrict__ start,
                                                float* __restrict__ neigh, int n)
{
    const int lane = threadIdx.x & 63;
    const int wid = threadIdx.x >> 6;
    const int node = blockIdx.x * 4 + wid;
    if (node >= n) return;
    const int s0 = start[node];
    const int s1 = start[node + 1];
    float2 m = make_float2(0.f, 0.f);
    for (int base = s0; base < s1; base += 64) {
        const int cnt = min(64, s1 - base);
        const int myidx = (base + lane < s1) ? csr_src[base + lane] : 0;
        int j = 0;
        for (; j + 2 <= cnt; j += 2) {
            const int sa = __shfl(myidx, j, 64);
            const int sb = __shfl(myidx, j + 1, 64);
            const float2 va = ((const float2*)(h + (size_t)sa * DF))[lane];
            const float2 vb = ((const float2*)(h + (size_t)sb * DF))[lane];
            m.x = fmaxf(m.x, fmaxf(va.x, vb.x));
            m.y = fmaxf(m.y, fmaxf(va.y, vb.y));
        }
        if (j < cnt) {
            const int sa = __shfl(myidx, j, 64);
            const float2 va = ((const float2*)(h + (size_t)sa * DF))[lane];
            m.x = fmaxf(m.x, va.x);
            m.y = fmaxf(m.y, va.y);
        }
    }
    ((float2*)(neigh + (size_t)node * DF))[lane] = m;
}

// ---------------- readout ----------------

__global__ __launch_bounds__(128) void colmax(const float* __restrict__ x,
                                              unsigned int* __restrict__ g, int nrows)
{
    const int c = threadIdx.x;
    float m = 0.f;
    for (int n = blockIdx.x; n < nrows; n += gridDim.x)
        m = fmaxf(m, x[(size_t)n * DF + c]);
    atomicMax(g + c, __float_as_uint(m));
}

__global__ __launch_bounds__(128) void head(const float* __restrict__ g,
                                            const float* __restrict__ Wfc1,
                                            const float* __restrict__ bfc1,
                                            const float* __restrict__ Wfc,
                                            const float* __restrict__ bfc,
                                            float* __restrict__ out)
{
    __shared__ float gsh[DF];
    __shared__ float tsh[DF];
    const int t = threadIdx.x;
    gsh[t] = g[t];
    __syncthreads();
    float acc = bfc1[t];
    #pragma unroll 8
    for (int k = 0; k < DF; ++k) acc = fmaf(gsh[k], Wfc1[k * DF + t], acc);
    tsh[t] = acc * Wfc[t];
    __syncthreads();
    if (t == 0) {
        float s = 0.f;
        for (int i = 0; i < DF; ++i) s += tsh[i];
        out[0] = s + bfc[0];
    }
}

extern "C" void kernel_launch(void* const* d_in, const int* in_sizes, int n_in,
                              void* d_out, int out_size, void* d_ws, size_t ws_size,
                              hipStream_t stream) {
    const float* x0     = (const float*)d_in[0];
    const int*   src    = (const int*)d_in[1];
    const int*   dst    = (const int*)d_in[2];
    const float* Wpool0 = (const float*)d_in[3];
    const float* bpool0 = (const float*)d_in[4];
    const float* Wself0 = (const float*)d_in[5];
    const float* Wneigh0= (const float*)d_in[6];
    const float* bias0  = (const float*)d_in[7];
    const float* gamma0 = (const float*)d_in[8];
    const float* beta0  = (const float*)d_in[9];
    const float* Wpool1 = (const float*)d_in[10];
    const float* bpool1 = (const float*)d_in[11];
    const float* Wself1 = (const float*)d_in[12];
    const float* Wneigh1= (const float*)d_in[13];
    const float* bias1  = (const float*)d_in[14];
    const float* gamma1 = (const float*)d_in[15];
    const float* beta1  = (const float*)d_in[16];
    const float* Wfc1   = (const float*)d_in[17];
    const float* bfc1   = (const float*)d_in[18];
    const float* Wfc    = (const float*)d_in[19];
    const float* bfc    = (const float*)d_in[20];

    const int N  = in_sizes[0] / DF;   // 50000
    const int nE = in_sizes[1];        // 800000
    const size_t bufElems = (size_t)N * DF;

    float* A = (float*)d_ws;                 // 25.6 MB each
    float* B = A + bufElems;
    float* C = B + bufElems;
    unsigned int* g = (unsigned int*)(C + bufElems);
    int* deg     = (int*)(g + DF);
    int* start   = deg + N;          // N+1 entries
    int* cursor  = start + N + 1;
    int* csr_src = cursor + N;       // nE entries
    // total ws: 76.8 MB + ~3.8 MB

    const dim3 gG((N + 127) / 128), bG(256);
    const dim3 gE((nE + 255) / 256);
    const dim3 gP((N + 3) / 4);

    // ---- CSR build (edge list shared by both layers) ----
    hipMemsetAsync(deg, 0, N * sizeof(int), stream);
    hist_deg<<<gE, 256, 0, stream>>>(dst, deg, nE);
    scan_deg<<<1, 1024, 0, stream>>>(deg, start, cursor, N);
    scatter_edges<<<gE, 256, 0, stream>>>(src, dst, cursor, csr_src, nE);

    // ---- layer 0 ----
    gemm128<1><<<gG, bG, 0, stream>>>(x0, Wpool0, bpool0, A, N);     // A = h0
    gemm128<0><<<gG, bG, 0, stream>>>(x0, Wself0, nullptr, B, N);    // B = x0@Wself0
    pull_max<<<gP, 256, 0, stream>>>(A, csr_src, start, C, N);       // C = neigh0
    gemm_ln<<<gG, bG, 0, stream>>>(C, Wneigh0, B, bias0, gamma0, beta0, A, N); // A = x1

    // ---- layer 1 ----
    gemm128<1><<<gG, bG, 0, stream>>>(A, Wpool1, bpool1, B, N);      // B = h1
    gemm128<0><<<gG, bG, 0, stream>>>(A, Wself1, nullptr, C, N);     // C = x1@Wself1
    pull_max<<<gP, 256, 0, stream>>>(B, csr_src, start, A, N);       // A = neigh1
    gemm_ln<<<gG, bG, 0, stream>>>(A, Wneigh1, C, bias1, gamma1, beta1, B, N); // B = x2

    // ---- readout ----
    hipMemsetAsync(g, 0, DF * sizeof(float), stream);
    colmax<<<512, 128, 0, stream>>>(B, g, N);
    head<<<1, 128, 0, stream>>>((const float*)g, Wfc1, bfc1, Wfc, bfc, (float*)d_out);
}

// Round 8
// 525.700 us; speedup vs baseline: 2.5983x; 1.1847x over previous
//
#include <hip/hip_runtime.h>

#define DF 128   // feature dim (both layers)

__device__ __forceinline__ float4 f4zero() { return make_float4(0.f, 0.f, 0.f, 0.f); }

// ---------------- GEMM kernels ----------------

// out = act(x @ W + b). MODE 0: plain. MODE 1: bias + relu.
template<int MODE>
__global__ __launch_bounds__(256) void gemm128(const float* __restrict__ x,
                                               const float* __restrict__ W,
                                               const float* __restrict__ b,
                                               float* __restrict__ out, int nrows)
{
    __shared__ float Ws[DF * DF];
    __shared__ float bs[DF];
    const int tid = threadIdx.x;
    {
        const float4* Wv = (const float4*)W;
        float4* Wsv = (float4*)Ws;
        #pragma unroll 4
        for (int i = tid; i < DF * DF / 4; i += 256) Wsv[i] = Wv[i];
        if (MODE == 1 && tid < DF / 4) ((float4*)bs)[tid] = ((const float4*)b)[tid];
    }
    __syncthreads();

    const int r = tid & 63;
    const int q = tid >> 6;
    const int row0 = blockIdx.x * 128 + r;
    const int row1 = row0 + 64;
    const int rl0 = min(row0, nrows - 1);
    const int rl1 = min(row1, nrows - 1);
    const float4* xp0 = (const float4*)(x + (size_t)rl0 * DF);
    const float4* xp1 = (const float4*)(x + (size_t)rl1 * DF);

    float4 acc0[8], acc1[8];
    #pragma unroll
    for (int j = 0; j < 8; ++j) { acc0[j] = f4zero(); acc1[j] = f4zero(); }

    #pragma unroll 4
    for (int k0 = 0; k0 < DF; k0 += 4) {
        float4 xa = xp0[k0 >> 2];
        float4 xb = xp1[k0 >> 2];
        const float ax[4] = {xa.x, xa.y, xa.z, xa.w};
        const float bx[4] = {xb.x, xb.y, xb.z, xb.w};
        #pragma unroll
        for (int dk = 0; dk < 4; ++dk) {
            const float4* wr = (const float4*)&Ws[(k0 + dk) * DF + (q << 5)];
            #pragma unroll
            for (int j = 0; j < 8; ++j) {
                float4 w = wr[j];
                acc0[j].x = fmaf(ax[dk], w.x, acc0[j].x);
                acc0[j].y = fmaf(ax[dk], w.y, acc0[j].y);
                acc0[j].z = fmaf(ax[dk], w.z, acc0[j].z);
                acc0[j].w = fmaf(ax[dk], w.w, acc0[j].w);
                acc1[j].x = fmaf(bx[dk], w.x, acc1[j].x);
                acc1[j].y = fmaf(bx[dk], w.y, acc1[j].y);
                acc1[j].z = fmaf(bx[dk], w.z, acc1[j].z);
                acc1[j].w = fmaf(bx[dk], w.w, acc1[j].w);
            }
        }
    }

    if (row0 < nrows) {
        float4* o = (float4*)(out + (size_t)row0 * DF + (q << 5));
        #pragma unroll
        for (int j = 0; j < 8; ++j) {
            float4 t = acc0[j];
            if (MODE == 1) {
                const int c = (q << 5) + 4 * j;
                t.x = fmaxf(t.x + bs[c + 0], 0.f);
                t.y = fmaxf(t.y + bs[c + 1], 0.f);
                t.z = fmaxf(t.z + bs[c + 2], 0.f);
                t.w = fmaxf(t.w + bs[c + 3], 0.f);
            }
            o[j] = t;
        }
    }
    if (row1 < nrows) {
        float4* o = (float4*)(out + (size_t)row1 * DF + (q << 5));
        #pragma unroll
        for (int j = 0; j < 8; ++j) {
            float4 t = acc1[j];
            if (MODE == 1) {
                const int c = (q << 5) + 4 * j;
                t.x = fmaxf(t.x + bs[c + 0], 0.f);
                t.y = fmaxf(t.y + bs[c + 1], 0.f);
                t.z = fmaxf(t.z + bs[c + 2], 0.f);
                t.w = fmaxf(t.w + bs[c + 3], 0.f);
            }
            o[j] = t;
        }
    }
}

// out = relu(LN(neigh @ Wneigh + xs + bias) * gamma + beta)
__global__ __launch_bounds__(256) void gemm_ln(const float* __restrict__ neigh,
                                               const float* __restrict__ W,
                                               const float* __restrict__ xs,
                                               const float* __restrict__ bias,
                                               const float* __restrict__ gamma,
                                               const float* __restrict__ beta,
                                               float* __restrict__ out, int nrows)
{
    __shared__ float Ws[DF * DF];
    __shared__ float bs[DF], gs[DF], bts[DF];
    __shared__ float redS[4][DF], redQ[4][DF];
    const int tid = threadIdx.x;
    {
        const float4* Wv = (const float4*)W;
        float4* Wsv = (float4*)Ws;
        #pragma unroll 4
        for (int i = tid; i < DF * DF / 4; i += 256) Wsv[i] = Wv[i];
        if (tid < DF / 4) {
            ((float4*)bs)[tid]  = ((const float4*)bias)[tid];
            ((float4*)gs)[tid]  = ((const float4*)gamma)[tid];
            ((float4*)bts)[tid] = ((const float4*)beta)[tid];
        }
    }
    __syncthreads();

    const int r = tid & 63;
    const int q = tid >> 6;
    const int row0 = blockIdx.x * 128 + r;
    const int row1 = row0 + 64;
    const int rl0 = min(row0, nrows - 1);
    const int rl1 = min(row1, nrows - 1);
    const float4* xp0 = (const float4*)(neigh + (size_t)rl0 * DF);
    const float4* xp1 = (const float4*)(neigh + (size_t)rl1 * DF);

    float4 acc0[8], acc1[8];
    #pragma unroll
    for (int j = 0; j < 8; ++j) { acc0[j] = f4zero(); acc1[j] = f4zero(); }

    #pragma unroll 4
    for (int k0 = 0; k0 < DF; k0 += 4) {
        float4 xa = xp0[k0 >> 2];
        float4 xb = xp1[k0 >> 2];
        const float ax[4] = {xa.x, xa.y, xa.z, xa.w};
        const float bx[4] = {xb.x, xb.y, xb.z, xb.w};
        #pragma unroll
        for (int dk = 0; dk < 4; ++dk) {
            const float4* wr = (const float4*)&Ws[(k0 + dk) * DF + (q << 5)];
            #pragma unroll
            for (int j = 0; j < 8; ++j) {
                float4 w = wr[j];
                acc0[j].x = fmaf(ax[dk], w.x, acc0[j].x);
                acc0[j].y = fmaf(ax[dk], w.y, acc0[j].y);
                acc0[j].z = fmaf(ax[dk], w.z, acc0[j].z);
                acc0[j].w = fmaf(ax[dk], w.w, acc0[j].w);
                acc1[j].x = fmaf(bx[dk], w.x, acc1[j].x);
                acc1[j].y = fmaf(bx[dk], w.y, acc1[j].y);
                acc1[j].z = fmaf(bx[dk], w.z, acc1[j].z);
                acc1[j].w = fmaf(bx[dk], w.w, acc1[j].w);
            }
        }
    }

    const float4* xsp0 = (const float4*)(xs + (size_t)rl0 * DF + (q << 5));
    const float4* xsp1 = (const float4*)(xs + (size_t)rl1 * DF + (q << 5));
    float s1a = 0.f, s2a = 0.f, s1b = 0.f, s2b = 0.f;
    #pragma unroll
    for (int j = 0; j < 8; ++j) {
        const int c = (q << 5) + 4 * j;
        float4 xv = xsp0[j];
        float4 t = acc0[j];
        t.x += xv.x + bs[c + 0]; t.y += xv.y + bs[c + 1];
        t.z += xv.z + bs[c + 2]; t.w += xv.w + bs[c + 3];
        acc0[j] = t;
        s1a += t.x + t.y + t.z + t.w;
        s2a += t.x * t.x + t.y * t.y + t.z * t.z + t.w * t.w;
        float4 yv = xsp1[j];
        float4 u = acc1[j];
        u.x += yv.x + bs[c + 0]; u.y += yv.y + bs[c + 1];
        u.z += yv.z + bs[c + 2]; u.w += yv.w + bs[c + 3];
        acc1[j] = u;
        s1b += u.x + u.y + u.z + u.w;
        s2b += u.x * u.x + u.y * u.y + u.z * u.z + u.w * u.w;
    }
    redS[q][r] = s1a; redQ[q][r] = s2a;
    redS[q][r + 64] = s1b; redQ[q][r + 64] = s2b;
    __syncthreads();

    const float mu0  = (redS[0][r] + redS[1][r] + redS[2][r] + redS[3][r]) * (1.f / 128.f);
    const float ex20 = (redQ[0][r] + redQ[1][r] + redQ[2][r] + redQ[3][r]) * (1.f / 128.f);
    const float inv0 = rsqrtf(ex20 - mu0 * mu0 + 1e-5f);
    const float mu1  = (redS[0][r+64] + redS[1][r+64] + redS[2][r+64] + redS[3][r+64]) * (1.f / 128.f);
    const float ex21 = (redQ[0][r+64] + redQ[1][r+64] + redQ[2][r+64] + redQ[3][r+64]) * (1.f / 128.f);
    const float inv1 = rsqrtf(ex21 - mu1 * mu1 + 1e-5f);

    if (row0 < nrows) {
        float4* o = (float4*)(out + (size_t)row0 * DF + (q << 5));
        #pragma unroll
        for (int j = 0; j < 8; ++j) {
            const int c = (q << 5) + 4 * j;
            float4 t = acc0[j];
            t.x = fmaxf((t.x - mu0) * inv0 * gs[c + 0] + bts[c + 0], 0.f);
            t.y = fmaxf((t.y - mu0) * inv0 * gs[c + 1] + bts[c + 1], 0.f);
            t.z = fmaxf((t.z - mu0) * inv0 * gs[c + 2] + bts[c + 2], 0.f);
            t.w = fmaxf((t.w - mu0) * inv0 * gs[c + 3] + bts[c + 3], 0.f);
            o[j] = t;
        }
    }
    if (row1 < nrows) {
        float4* o = (float4*)(out + (size_t)row1 * DF + (q << 5));
        #pragma unroll
        for (int j = 0; j < 8; ++j) {
            const int c = (q << 5) + 4 * j;
            float4 t = acc1[j];
            t.x = fmaxf((t.x - mu1) * inv1 * gs[c + 0] + bts[c + 0], 0.f);
            t.y = fmaxf((t.y - mu1) * inv1 * gs[c + 1] + bts[c + 1], 0.f);
            t.z = fmaxf((t.z - mu1) * inv1 * gs[c + 2] + bts[c + 2], 0.f);
            t.w = fmaxf((t.w - mu1) * inv1 * gs[c + 3] + bts[c + 3], 0.f);
            o[j] = t;
        }
    }
}

// ---------------- CSR build (counting sort by dst; built once, used twice) ----------------

__global__ __launch_bounds__(256) void hist_deg(const int* __restrict__ dst,
                                                int* __restrict__ deg, int nE)
{
    const int e = blockIdx.x * 256 + threadIdx.x;
    if (e < nE) atomicAdd(&deg[dst[e]], 1);
}

// Device-wide exclusive scan, 3 coalesced kernels. TILE = 1024 elems/block (256 thr x int4).
__global__ __launch_bounds__(256) void scan_partials(const int* __restrict__ deg,
                                                     int* __restrict__ part, int n)
{
    __shared__ int red[256];
    const int t = threadIdx.x;
    const int base = blockIdx.x * 1024 + t * 4;
    int4 v = make_int4(0, 0, 0, 0);
    if (base + 3 < n) v = *(const int4*)(deg + base);
    else {
        if (base     < n) v.x = deg[base];
        if (base + 1 < n) v.y = deg[base + 1];
        if (base + 2 < n) v.z = deg[base + 2];
        if (base + 3 < n) v.w = deg[base + 3];
    }
    red[t] = v.x + v.y + v.z + v.w;
    __syncthreads();
    for (int off = 128; off > 0; off >>= 1) {
        if (t < off) red[t] += red[t + off];
        __syncthreads();
    }
    if (t == 0) part[blockIdx.x] = red[0];
}

// single block: exclusive-scan part[0..nb) in place (nb <= 256)
__global__ __launch_bounds__(256) void scan_mid(int* __restrict__ part, int nb)
{
    __shared__ int s[256];
    const int t = threadIdx.x;
    const int orig = (t < nb) ? part[t] : 0;
    s[t] = orig;
    __syncthreads();
    int acc = orig;
    for (int off = 1; off < 256; off <<= 1) {
        const int tmp = (t >= off) ? s[t - off] : 0;
        __syncthreads();
        s[t] += tmp;
        __syncthreads();
    }
    if (t < nb) part[t] = s[t] - orig;   // exclusive
}

__global__ __launch_bounds__(256) void scan_final(const int* __restrict__ deg,
                                                  const int* __restrict__ part,
                                                  int* __restrict__ start,
                                                  int* __restrict__ cursor,
                                                  int n, int nE)
{
    __shared__ int red[256];
    const int t = threadIdx.x;
    const int base = blockIdx.x * 1024 + t * 4;
    int4 v = make_int4(0, 0, 0, 0);
    if (base + 3 < n) v = *(const int4*)(deg + base);
    else {
        if (base     < n) v.x = deg[base];
        if (base + 1 < n) v.y = deg[base + 1];
        if (base + 2 < n) v.z = deg[base + 2];
        if (base + 3 < n) v.w = deg[base + 3];
    }
    const int s = v.x + v.y + v.z + v.w;
    red[t] = s;
    __syncthreads();
    for (int off = 1; off < 256; off <<= 1) {
        const int tmp = (t >= off) ? red[t - off] : 0;
        __syncthreads();
        red[t] += tmp;
        __syncthreads();
    }
    int excl = red[t] - s + part[blockIdx.x];
    int4 o;
    o.x = excl;
    o.y = o.x + v.x;
    o.z = o.y + v.y;
    o.w = o.z + v.z;
    if (base + 3 < n) {
        *(int4*)(start + base) = o;
        *(int4*)(cursor + base) = o;
    } else {
        if (base     < n) { start[base]     = o.x; cursor[base]     = o.x; }
        if (base + 1 < n) { start[base + 1] = o.y; cursor[base + 1] = o.y; }
        if (base + 2 < n) { start[base + 2] = o.z; cursor[base + 2] = o.z; }
        if (base + 3 < n) { start[base + 3] = o.w; cursor[base + 3] = o.w; }
    }
    if (blockIdx.x == 0 && t == 0) start[n] = nE;
}

__global__ __launch_bounds__(256) void scatter_edges(const int* __restrict__ src,
                                                     const int* __restrict__ dst,
                                                     int* __restrict__ cursor,
                                                     int* __restrict__ csr_src, int nE)
{
    const int e = blockIdx.x * 256 + threadIdx.x;
    if (e < nE) {
        const int p = atomicAdd(&cursor[dst[e]], 1);
        csr_src[p] = src[e];   // order within a node is arbitrary; max is commutative
    }
}

// ---------------- pull-based segment max: neigh[n] = max over in-edges of h[src] ----------------
__global__ __launch_bounds__(256) void pull_max(const float* __restrict__ h,
                                                const int* __restrict__ csr_src,
                                                const int* __restrict__ start,
                                                float* __restrict__ neigh, int n)
{
    const int lane = threadIdx.x & 63;
    const int wid = threadIdx.x >> 6;
    const int node = blockIdx.x * 4 + wid;
    if (node >= n) return;
    const int s0 = start[node];
    const int s1 = start[node + 1];
    float2 m = make_float2(0.f, 0.f);
    for (int base = s0; base < s1; base += 64) {
        const int cnt = min(64, s1 - base);
        const int myidx = (base + lane < s1) ? csr_src[base + lane] : 0;
        int j = 0;
        for (; j + 2 <= cnt; j += 2) {
            const int sa = __shfl(myidx, j, 64);
            const int sb = __shfl(myidx, j + 1, 64);
            const float2 va = ((const float2*)(h + (size_t)sa * DF))[lane];
            const float2 vb = ((const float2*)(h + (size_t)sb * DF))[lane];
            m.x = fmaxf(m.x, fmaxf(va.x, vb.x));
            m.y = fmaxf(m.y, fmaxf(va.y, vb.y));
        }
        if (j < cnt) {
            const int sa = __shfl(myidx, j, 64);
            const float2 va = ((const float2*)(h + (size_t)sa * DF))[lane];
            m.x = fmaxf(m.x, va.x);
            m.y = fmaxf(m.y, va.y);
        }
    }
    ((float2*)(neigh + (size_t)node * DF))[lane] = m;
}

// ---------------- readout ----------------

__global__ __launch_bounds__(128) void colmax(const float* __restrict__ x,
                                              unsigned int* __restrict__ g, int nrows)
{
    const int c = threadIdx.x;
    float m = 0.f;
    for (int n = blockIdx.x; n < nrows; n += gridDim.x)
        m = fmaxf(m, x[(size_t)n * DF + c]);
    atomicMax(g + c, __float_as_uint(m));
}

__global__ __launch_bounds__(128) void head(const float* __restrict__ g,
                                            const float* __restrict__ Wfc1,
                                            const float* __restrict__ bfc1,
                                            const float* __restrict__ Wfc,
                                            const float* __restrict__ bfc,
                                            float* __restrict__ out)
{
    __shared__ float gsh[DF];
    __shared__ float tsh[DF];
    const int t = threadIdx.x;
    gsh[t] = g[t];
    __syncthreads();
    float acc = bfc1[t];
    #pragma unroll 8
    for (int k = 0; k < DF; ++k) acc = fmaf(gsh[k], Wfc1[k * DF + t], acc);
    tsh[t] = acc * Wfc[t];
    __syncthreads();
    if (t == 0) {
        float s = 0.f;
        for (int i = 0; i < DF; ++i) s += tsh[i];
        out[0] = s + bfc[0];
    }
}

extern "C" void kernel_launch(void* const* d_in, const int* in_sizes, int n_in,
                              void* d_out, int out_size, void* d_ws, size_t ws_size,
                              hipStream_t stream) {
    const float* x0     = (const float*)d_in[0];
    const int*   src    = (const int*)d_in[1];
    const int*   dst    = (const int*)d_in[2];
    const float* Wpool0 = (const float*)d_in[3];
    const float* bpool0 = (const float*)d_in[4];
    const float* Wself0 = (const float*)d_in[5];
    const float* Wneigh0= (const float*)d_in[6];
    const float* bias0  = (const float*)d_in[7];
    const float* gamma0 = (const float*)d_in[8];
    const float* beta0  = (const float*)d_in[9];
    const float* Wpool1 = (const float*)d_in[10];
    const float* bpool1 = (const float*)d_in[11];
    const float* Wself1 = (const float*)d_in[12];
    const float* Wneigh1= (const float*)d_in[13];
    const float* bias1  = (const float*)d_in[14];
    const float* gamma1 = (const float*)d_in[15];
    const float* beta1  = (const float*)d_in[16];
    const float* Wfc1   = (const float*)d_in[17];
    const float* bfc1   = (const float*)d_in[18];
    const float* Wfc    = (const float*)d_in[19];
    const float* bfc    = (const float*)d_in[20];

    const int N  = in_sizes[0] / DF;   // 50000
    const int nE = in_sizes[1];        // 800000
    const size_t bufElems = (size_t)N * DF;

    float* A = (float*)d_ws;                 // 25.6 MB each
    float* B = A + bufElems;
    float* C = B + bufElems;
    unsigned int* g = (unsigned int*)(C + bufElems);
    int* deg     = (int*)(g + DF);
    int* start   = deg + N;          // N+1 entries
    int* cursor  = start + N + 1;
    int* csr_src = cursor + N;       // nE entries
    int* part    = csr_src + nE;     // <=256 entries

    const dim3 gG((N + 127) / 128), bG(256);
    const dim3 gE((nE + 255) / 256);
    const dim3 gP((N + 3) / 4);
    const int nb = (N + 1023) / 1024;   // scan blocks (49 for N=50000)

    // ---- CSR build (edge list shared by both layers) ----
    hipMemsetAsync(deg, 0, N * sizeof(int), stream);
    hist_deg<<<gE, 256, 0, stream>>>(dst, deg, nE);
    scan_partials<<<nb, 256, 0, stream>>>(deg, part, N);
    scan_mid<<<1, 256, 0, stream>>>(part, nb);
    scan_final<<<nb, 256, 0, stream>>>(deg, part, start, cursor, N, nE);
    scatter_edges<<<gE, 256, 0, stream>>>(src, dst, cursor, csr_src, nE);

    // ---- layer 0 ----
    gemm128<1><<<gG, bG, 0, stream>>>(x0, Wpool0, bpool0, A, N);     // A = h0
    gemm128<0><<<gG, bG, 0, stream>>>(x0, Wself0, nullptr, B, N);    // B = x0@Wself0
    pull_max<<<gP, 256, 0, stream>>>(A, csr_src, start, C, N);       // C = neigh0
    gemm_ln<<<gG, bG, 0, stream>>>(C, Wneigh0, B, bias0, gamma0, beta0, A, N); // A = x1

    // ---- layer 1 ----
    gemm128<1><<<gG, bG, 0, stream>>>(A, Wpool1, bpool1, B, N);      // B = h1
    gemm128<0><<<gG, bG, 0, stream>>>(A, Wself1, nullptr, C, N);     // C = x1@Wself1
    pull_max<<<gP, 256, 0, stream>>>(B, csr_src, start, A, N);       // A = neigh1
    gemm_ln<<<gG, bG, 0, stream>>>(A, Wneigh1, C, bias1, gamma1, beta1, B, N); // B = x2

    // ---- readout ----
    hipMemsetAsync(g, 0, DF * sizeof(float), stream);
    colmax<<<512, 128, 0, stream>>>(B, g, N);
    head<<<1, 128, 0, stream>>>((const float*)g, Wfc1, bfc1, Wfc, bfc, (float*)d_out);
}

// Round 10
// 273.561 us; speedup vs baseline: 4.9931x; 1.9217x over previous
//
#include <hip/hip_runtime.h>

#define DF 128

typedef __attribute__((ext_vector_type(8))) short short8;
typedef __attribute__((ext_vector_type(4))) float f32x4;

__device__ __forceinline__ ushort f2bf(float f) {
    unsigned u = __float_as_uint(f);
    return (ushort)((u + 0x7fffu + ((u >> 16) & 1u)) >> 16);   // RNE
}
__device__ __forceinline__ float bf2f(ushort h) {
    return __uint_as_float(((unsigned)h) << 16);
}

// ---------------- prep: fp32 -> bf16 activation convert ----------------
__global__ __launch_bounds__(256) void convert_bf16(const float* __restrict__ in,
                                                    ushort* __restrict__ out, int n8)
{
    const int i = blockIdx.x * 256 + threadIdx.x;
    if (i >= n8) return;
    const float4* p = (const float4*)(in + (size_t)i * 8);
    float4 a = p[0], b = p[1];
    uint4 o;
    o.x = f2bf(a.x) | ((unsigned)f2bf(a.y) << 16);
    o.y = f2bf(a.z) | ((unsigned)f2bf(a.w) << 16);
    o.z = f2bf(b.x) | ((unsigned)f2bf(b.y) << 16);
    o.w = f2bf(b.z) | ((unsigned)f2bf(b.w) << 16);
    ((uint4*)out)[i] = o;
}

// ---------------- prep: weights -> MFMA-fragment-ordered bf16 ----------------
// Entry e = (kstep, cb, lane): holds B-frag 8 bf16: W[k0..k0+7][cb*16 + (lane&15)],
// k0 = kstep*32 + (lane>>4)*8. k<128 from Wa, k>=128 from Wb ([Wself;Wneigh] concat).
__global__ __launch_bounds__(256) void prep_frag(const float* __restrict__ Wa,
                                                 const float* __restrict__ Wb,
                                                 ushort* __restrict__ out, int nent)
{
    const int e = blockIdx.x * 256 + threadIdx.x;
    if (e >= nent) return;
    const int kstep = e >> 9;
    const int cb = (e >> 6) & 7;
    const int lane = e & 63;
    const int c = cb * 16 + (lane & 15);
    const int k0 = kstep * 32 + ((lane >> 4) << 3);
    ushort r[8];
    #pragma unroll
    for (int i = 0; i < 8; ++i) {
        const int k = k0 + i;
        const float v = (k < DF) ? Wa[k * DF + c] : Wb[(k - DF) * DF + c];
        r[i] = f2bf(v);
    }
    uint4 o;
    o.x = r[0] | ((unsigned)r[1] << 16);
    o.y = r[2] | ((unsigned)r[3] << 16);
    o.z = r[4] | ((unsigned)r[5] << 16);
    o.w = r[6] | ((unsigned)r[7] << 16);
    ((uint4*)out)[e] = o;
}

// ---------------- MFMA pool GEMM: out = relu(x @ Wpool + b), bf16 in/out ----------------
// 256 thr = 4 waves; block = 64 rows (16/wave); wave covers all 128 cols (8 cb frags).
__global__ __launch_bounds__(256) void gemm_pool(const ushort* __restrict__ xb,
                                                 const ushort* __restrict__ wf,
                                                 const float* __restrict__ bias,
                                                 ushort* __restrict__ out, int nrows)
{
    __shared__ ushort wl[16384];   // 4 ksteps * 8 cb * 64 lanes * 8 bf16 = 32 KB; reused as out staging
    __shared__ float bs[DF];
    const int tid = threadIdx.x;
    {
        const uint4* s = (const uint4*)wf;
        uint4* d = (uint4*)wl;
        #pragma unroll
        for (int i = 0; i < 8; ++i) d[tid + 256 * i] = s[tid + 256 * i];
        if (tid < DF) bs[tid] = bias[tid];
    }
    __syncthreads();

    const int lane = tid & 63;
    const int w = tid >> 6;
    const int row16 = blockIdx.x * 64 + w * 16;
    const int arow = min(row16 + (lane & 15), nrows - 1);
    const ushort* ap = xb + (size_t)arow * DF + ((lane >> 4) << 3);

    f32x4 acc[8];
    #pragma unroll
    for (int cb = 0; cb < 8; ++cb) acc[cb] = (f32x4){0.f, 0.f, 0.f, 0.f};

    #pragma unroll
    for (int ks = 0; ks < 4; ++ks) {
        const short8 a = *(const short8*)(ap + ks * 32);
        #pragma unroll
        for (int cb = 0; cb < 8; ++cb) {
            const short8 b = ((const short8*)wl)[(ks * 8 + cb) * 64 + lane];
            acc[cb] = __builtin_amdgcn_mfma_f32_16x16x32_bf16(a, b, acc[cb], 0, 0, 0);
        }
    }
    __syncthreads();   // wl dead as weights; reuse as out staging

    ushort* ol = wl;
    #pragma unroll
    for (int cb = 0; cb < 8; ++cb) {
        const int c = (lane & 15) + (cb << 4);
        const float bv = bs[c];
        #pragma unroll
        for (int reg = 0; reg < 4; ++reg) {
            const int m = ((lane >> 4) << 2) + reg;
            ol[(w * 16 + m) * DF + c] = f2bf(fmaxf(acc[cb][reg] + bv, 0.f));
        }
    }
    __syncthreads();

    const int rowbase = blockIdx.x * 64;
    uint4* og = (uint4*)(out + (size_t)rowbase * DF);
    const uint4* olv = (const uint4*)wl;
    #pragma unroll
    for (int i = 0; i < 4; ++i) {
        const int j = tid + 256 * i;           // 1024 uint4 = 64 rows * 16
        if (rowbase + (j >> 4) < nrows) og[j] = olv[j];
    }
}

// ---------------- MFMA fused GEMM+LN: out = relu(LN(x@Wself + n@Wneigh + bias)) ----------------
// K=256: ksteps 0-3 read xb, 4-7 read nbuf. LN per-row fully in-wave.
__global__ __launch_bounds__(256) void gemm_fused_ln(const ushort* __restrict__ xb,
                                                     const ushort* __restrict__ nbuf,
                                                     const ushort* __restrict__ wf,
                                                     const float* __restrict__ bias,
                                                     const float* __restrict__ gamma,
                                                     const float* __restrict__ beta,
                                                     ushort* __restrict__ out, int nrows)
{
    __shared__ ushort wl[32768];   // 8 ksteps * 8 cb * 64 * 8 = 64 KB; reused as out staging
    __shared__ float bs[DF], gs[DF], bt[DF];
    const int tid = threadIdx.x;
    {
        const uint4* s = (const uint4*)wf;
        uint4* d = (uint4*)wl;
        #pragma unroll
        for (int i = 0; i < 16; ++i) d[tid + 256 * i] = s[tid + 256 * i];
        if (tid < DF) { bs[tid] = bias[tid]; gs[tid] = gamma[tid]; bt[tid] = beta[tid]; }
    }
    __syncthreads();

    const int lane = tid & 63;
    const int w = tid >> 6;
    const int row16 = blockIdx.x * 64 + w * 16;
    const int arow = min(row16 + (lane & 15), nrows - 1);
    const ushort* apx = xb + (size_t)arow * DF + ((lane >> 4) << 3);
    const ushort* apn = nbuf + (size_t)arow * DF + ((lane >> 4) << 3);

    f32x4 acc[8];
    #pragma unroll
    for (int cb = 0; cb < 8; ++cb) acc[cb] = (f32x4){0.f, 0.f, 0.f, 0.f};

    #pragma unroll
    for (int ks = 0; ks < 8; ++ks) {
        const short8 a = (ks < 4) ? *(const short8*)(apx + ks * 32)
                                  : *(const short8*)(apn + (ks - 4) * 32);
        #pragma unroll
        for (int cb = 0; cb < 8; ++cb) {
            const short8 b = ((const short8*)wl)[(ks * 8 + cb) * 64 + lane];
            acc[cb] = __builtin_amdgcn_mfma_f32_16x16x32_bf16(a, b, acc[cb], 0, 0, 0);
        }
    }

    // + bias, then LN stats per row (row = (lane>>4)*4+reg; 16 lanes share a row)
    #pragma unroll
    for (int cb = 0; cb < 8; ++cb) {
        const float bv = bs[(lane & 15) + (cb << 4)];
        #pragma unroll
        for (int reg = 0; reg < 4; ++reg) acc[cb][reg] += bv;
    }
    float mu[4], inv[4];
    #pragma unroll
    for (int reg = 0; reg < 4; ++reg) {
        float s1 = 0.f, s2 = 0.f;
        #pragma unroll
        for (int cb = 0; cb < 8; ++cb) { const float f = acc[cb][reg]; s1 += f; s2 += f * f; }
        #pragma unroll
        for (int m = 1; m < 16; m <<= 1) { s1 += __shfl_xor(s1, m, 64); s2 += __shfl_xor(s2, m, 64); }
        mu[reg] = s1 * (1.f / 128.f);
        inv[reg] = rsqrtf(s2 * (1.f / 128.f) - mu[reg] * mu[reg] + 1e-5f);
    }
    __syncthreads();   // wl weights dead; reuse as out staging

    ushort* ol = wl;
    #pragma unroll
    for (int cb = 0; cb < 8; ++cb) {
        const int c = (lane & 15) + (cb << 4);
        const float gv = gs[c], btv = bt[c];
        #pragma unroll
        for (int reg = 0; reg < 4; ++reg) {
            const int m = ((lane >> 4) << 2) + reg;
            const float v = (acc[cb][reg] - mu[reg]) * inv[reg] * gv + btv;
            ol[(w * 16 + m) * DF + c] = f2bf(fmaxf(v, 0.f));
        }
    }
    __syncthreads();

    const int rowbase = blockIdx.x * 64;
    uint4* og = (uint4*)(out + (size_t)rowbase * DF);
    const uint4* olv = (const uint4*)wl;
    #pragma unroll
    for (int i = 0; i < 4; ++i) {
        const int j = tid + 256 * i;
        if (rowbase + (j >> 4) < nrows) og[j] = olv[j];
    }
}

// ---------------- CSR build (unchanged; passed in R7/R8) ----------------
__global__ __launch_bounds__(256) void hist_deg(const int* __restrict__ dst,
                                                int* __restrict__ deg, int nE)
{
    const int e = blockIdx.x * 256 + threadIdx.x;
    if (e < nE) atomicAdd(&deg[dst[e]], 1);
}

__global__ __launch_bounds__(256) void scan_partials(const int* __restrict__ deg,
                                                     int* __restrict__ part, int n)
{
    __shared__ int red[256];
    const int t = threadIdx.x;
    const int base = blockIdx.x * 1024 + t * 4;
    int4 v = make_int4(0, 0, 0, 0);
    if (base + 3 < n) v = *(const int4*)(deg + base);
    else {
        if (base     < n) v.x = deg[base];
        if (base + 1 < n) v.y = deg[base + 1];
        if (base + 2 < n) v.z = deg[base + 2];
        if (base + 3 < n) v.w = deg[base + 3];
    }
    red[t] = v.x + v.y + v.z + v.w;
    __syncthreads();
    for (int off = 128; off > 0; off >>= 1) {
        if (t < off) red[t] += red[t + off];
        __syncthreads();
    }
    if (t == 0) part[blockIdx.x] = red[0];
}

__global__ __launch_bounds__(256) void scan_mid(int* __restrict__ part, int nb)
{
    __shared__ int s[256];
    const int t = threadIdx.x;
    const int orig = (t < nb) ? part[t] : 0;
    s[t] = orig;
    __syncthreads();
    for (int off = 1; off < 256; off <<= 1) {
        const int tmp = (t >= off) ? s[t - off] : 0;
        __syncthreads();
        s[t] += tmp;
        __syncthreads();
    }
    if (t < nb) part[t] = s[t] - orig;
}

__global__ __launch_bounds__(256) void scan_final(const int* __restrict__ deg,
                                                  const int* __restrict__ part,
                                                  int* __restrict__ start,
                                                  int* __restrict__ cursor,
                                                  int n, int nE)
{
    __shared__ int red[256];
    const int t = threadIdx.x;
    const int base = blockIdx.x * 1024 + t * 4;
    int4 v = make_int4(0, 0, 0, 0);
    if (base + 3 < n) v = *(const int4*)(deg + base);
    else {
        if (base     < n) v.x = deg[base];
        if (base + 1 < n) v.y = deg[base + 1];
        if (base + 2 < n) v.z = deg[base + 2];
        if (base + 3 < n) v.w = deg[base + 3];
    }
    const int s = v.x + v.y + v.z + v.w;
    red[t] = s;
    __syncthreads();
    for (int off = 1; off < 256; off <<= 1) {
        const int tmp = (t >= off) ? red[t - off] : 0;
        __syncthreads();
        red[t] += tmp;
        __syncthreads();
    }
    int excl = red[t] - s + part[blockIdx.x];
    int4 o;
    o.x = excl; o.y = o.x + v.x; o.z = o.y + v.y; o.w = o.z + v.z;
    if (base + 3 < n) {
        *(int4*)(start + base) = o;
        *(int4*)(cursor + base) = o;
    } else {
        if (base     < n) { start[base]     = o.x; cursor[base]     = o.x; }
        if (base + 1 < n) { start[base + 1] = o.y; cursor[base + 1] = o.y; }
        if (base + 2 < n) { start[base + 2] = o.z; cursor[base + 2] = o.z; }
        if (base + 3 < n) { start[base + 3] = o.w; cursor[base + 3] = o.w; }
    }
    if (blockIdx.x == 0 && t == 0) start[n] = nE;
}

__global__ __launch_bounds__(256) void scatter_edges(const int* __restrict__ src,
                                                     const int* __restrict__ dst,
                                                     int* __restrict__ cursor,
                                                     int* __restrict__ csr_src, int nE)
{
    const int e = blockIdx.x * 256 + threadIdx.x;
    if (e < nE) {
        const int p = atomicAdd(&cursor[dst[e]], 1);
        csr_src[p] = src[e];
    }
}

// ---------------- pull max (bf16): neigh[n] = elementwise max over in-edges of h[src] ----------------
// bf16 >= 0 -> ushort compare is exact. 1 wave/node, uint (2 bf16) per lane.
__global__ __launch_bounds__(256) void pull_max(const ushort* __restrict__ h,
                                                const int* __restrict__ csr_src,
                                                const int* __restrict__ start,
                                                ushort* __restrict__ neigh, int n)
{
    const int lane = threadIdx.x & 63;
    const int wid = threadIdx.x >> 6;
    const int node = blockIdx.x * 4 + wid;
    if (node >= n) return;
    const int s0 = start[node];
    const int s1 = start[node + 1];
    unsigned mlo = 0, mhi = 0;
    for (int base = s0; base < s1; base += 64) {
        const int cnt = min(64, s1 - base);
        const int myidx = (base + lane < s1) ? csr_src[base + lane] : 0;
        int j = 0;
        for (; j + 2 <= cnt; j += 2) {
            const int sa = __shfl(myidx, j, 64);
            const int sb = __shfl(myidx, j + 1, 64);
            const unsigned va = ((const unsigned*)(h + (size_t)sa * DF))[lane];
            const unsigned vb = ((const unsigned*)(h + (size_t)sb * DF))[lane];
            mlo = max(mlo, max(va & 0xffffu, vb & 0xffffu));
            mhi = max(mhi, max(va >> 16, vb >> 16));
        }
        if (j < cnt) {
            const int sa = __shfl(myidx, j, 64);
            const unsigned va = ((const unsigned*)(h + (size_t)sa * DF))[lane];
            mlo = max(mlo, va & 0xffffu);
            mhi = max(mhi, va >> 16);
        }
    }
    ((unsigned*)(neigh + (size_t)node * DF))[lane] = mlo | (mhi << 16);
}

// ---------------- readout ----------------
__global__ __launch_bounds__(128) void colmax(const ushort* __restrict__ x,
                                              unsigned* __restrict__ g, int nrows)
{
    const int c = threadIdx.x;
    float m = 0.f;
    for (int n = blockIdx.x; n < nrows; n += gridDim.x)
        m = fmaxf(m, bf2f(x[(size_t)n * DF + c]));
    atomicMax(g + c, __float_as_uint(m));
}

__global__ __launch_bounds__(128) void head(const float* __restrict__ g,
                                            const float* __restrict__ Wfc1,
                                            const float* __restrict__ bfc1,
                                            const float* __restrict__ Wfc,
                                            const float* __restrict__ bfc,
                                            float* __restrict__ out)
{
    __shared__ float gsh[DF];
    __shared__ float tsh[DF];
    const int t = threadIdx.x;
    gsh[t] = g[t];
    __syncthreads();
    float acc = bfc1[t];
    #pragma unroll 8
    for (int k = 0; k < DF; ++k) acc = fmaf(gsh[k], Wfc1[k * DF + t], acc);
    tsh[t] = acc * Wfc[t];
    __syncthreads();
    if (t == 0) {
        float s = 0.f;
        for (int i = 0; i < DF; ++i) s += tsh[i];
        out[0] = s + bfc[0];
    }
}

extern "C" void kernel_launch(void* const* d_in, const int* in_sizes, int n_in,
                              void* d_out, int out_size, void* d_ws, size_t ws_size,
                              hipStream_t stream) {
    const float* x0     = (const float*)d_in[0];
    const int*   src    = (const int*)d_in[1];
    const int*   dst    = (const int*)d_in[2];
    const float* Wpool0 = (const float*)d_in[3];
    const float* bpool0 = (const float*)d_in[4];
    const float* Wself0 = (const float*)d_in[5];
    const float* Wneigh0= (const float*)d_in[6];
    const float* bias0  = (const float*)d_in[7];
    const float* gamma0 = (const float*)d_in[8];
    const float* beta0  = (const float*)d_in[9];
    const float* Wpool1 = (const float*)d_in[10];
    const float* bpool1 = (const float*)d_in[11];
    const float* Wself1 = (const float*)d_in[12];
    const float* Wneigh1= (const float*)d_in[13];
    const float* bias1  = (const float*)d_in[14];
    const float* gamma1 = (const float*)d_in[15];
    const float* beta1  = (const float*)d_in[16];
    const float* Wfc1   = (const float*)d_in[17];
    const float* bfc1   = (const float*)d_in[18];
    const float* Wfc    = (const float*)d_in[19];
    const float* bfc    = (const float*)d_in[20];

    const int N  = in_sizes[0] / DF;   // 50000
    const int nE = in_sizes[1];        // 800000
    const size_t bufElems = (size_t)N * DF;

    ushort* xb   = (ushort*)d_ws;        // 12.8 MB each
    ushort* x1b  = xb + bufElems;
    ushort* hb   = x1b + bufElems;
    ushort* nb   = hb + bufElems;
    ushort* wfp0 = nb + bufElems;        // 2048 entries * 8 ushort = 32 KB
    ushort* wfp1 = wfp0 + 16384;
    ushort* wfc0 = wfp1 + 16384;         // 4096 entries * 8 ushort = 64 KB
    ushort* wfc1 = wfc0 + 32768;
    unsigned* g  = (unsigned*)(wfc1 + 32768);
    int* deg     = (int*)(g + DF);
    int* start   = deg + N;
    int* cursor  = start + N + 1;
    int* csr_src = cursor + N;
    int* part    = csr_src + nE;

    const dim3 gE((nE + 255) / 256);
    const dim3 gP((N + 3) / 4);
    const dim3 gM((N + 63) / 64);        // 782 MFMA-GEMM blocks
    const int nb_scan = (N + 1023) / 1024;

    // ---- prep: bf16 input + fragment-ordered weights ----
    convert_bf16<<<(int)((bufElems / 8 + 255) / 256), 256, 0, stream>>>(x0, xb, (int)(bufElems / 8));
    prep_frag<<<8, 256, 0, stream>>>(Wpool0, Wpool0, wfp0, 2048);
    prep_frag<<<8, 256, 0, stream>>>(Wpool1, Wpool1, wfp1, 2048);
    prep_frag<<<16, 256, 0, stream>>>(Wself0, Wneigh0, wfc0, 4096);
    prep_frag<<<16, 256, 0, stream>>>(Wself1, Wneigh1, wfc1, 4096);

    // ---- CSR build ----
    hipMemsetAsync(deg, 0, N * sizeof(int), stream);
    hist_deg<<<gE, 256, 0, stream>>>(dst, deg, nE);
    scan_partials<<<nb_scan, 256, 0, stream>>>(deg, part, N);
    scan_mid<<<1, 256, 0, stream>>>(part, nb_scan);
    scan_final<<<nb_scan, 256, 0, stream>>>(deg, part, start, cursor, N, nE);
    scatter_edges<<<gE, 256, 0, stream>>>(src, dst, cursor, csr_src, nE);

    // ---- layer 0 ----
    gemm_pool<<<gM, 256, 0, stream>>>(xb, wfp0, bpool0, hb, N);
    pull_max<<<gP, 256, 0, stream>>>(hb, csr_src, start, nb, N);
    gemm_fused_ln<<<gM, 256, 0, stream>>>(xb, nb, wfc0, bias0, gamma0, beta0, x1b, N);

    // ---- layer 1 ----
    gemm_pool<<<gM, 256, 0, stream>>>(x1b, wfp1, bpool1, hb, N);
    pull_max<<<gP, 256, 0, stream>>>(hb, csr_src, start, nb, N);
    gemm_fused_ln<<<gM, 256, 0, stream>>>(x1b, nb, wfc1, bias1, gamma1, beta1, xb, N);  // x2 -> xb

    // ---- readout ----
    hipMemsetAsync(g, 0, DF * sizeof(float), stream);
    colmax<<<512, 128, 0, stream>>>(xb, g, N);
    head<<<1, 128, 0, stream>>>((const float*)g, Wfc1, bfc1, Wfc, bfc, (float*)d_out);
}

// Round 12
// 231.313 us; speedup vs baseline: 5.9050x; 1.1826x over previous
//
#include <hip/hip_runtime.h>

#define DF 128
#define SCHUNK 2048

typedef __attribute__((ext_vector_type(8))) short short8;
typedef __attribute__((ext_vector_type(4))) float f32x4;

__device__ __forceinline__ ushort f2bf(float f) {
    unsigned u = __float_as_uint(f);
    return (ushort)((u + 0x7fffu + ((u >> 16) & 1u)) >> 16);   // RNE
}
__device__ __forceinline__ float bf2f(ushort h) {
    return __uint_as_float(((unsigned)h) << 16);
}

// ---------------- prep: fp32 -> bf16 activation convert ----------------
__global__ __launch_bounds__(256) void convert_bf16(const float* __restrict__ in,
                                                    ushort* __restrict__ out, int n8)
{
    const int i = blockIdx.x * 256 + threadIdx.x;
    if (i >= n8) return;
    const float4* p = (const float4*)(in + (size_t)i * 8);
    float4 a = p[0], b = p[1];
    uint4 o;
    o.x = f2bf(a.x) | ((unsigned)f2bf(a.y) << 16);
    o.y = f2bf(a.z) | ((unsigned)f2bf(a.w) << 16);
    o.z = f2bf(b.x) | ((unsigned)f2bf(b.y) << 16);
    o.w = f2bf(b.z) | ((unsigned)f2bf(b.w) << 16);
    ((uint4*)out)[i] = o;
}

// ---------------- prep: weights -> MFMA-fragment-ordered bf16 ----------------
__global__ __launch_bounds__(256) void prep_frag(const float* __restrict__ Wa,
                                                 const float* __restrict__ Wb,
                                                 ushort* __restrict__ out, int nent)
{
    const int e = blockIdx.x * 256 + threadIdx.x;
    if (e >= nent) return;
    const int kstep = e >> 9;
    const int cb = (e >> 6) & 7;
    const int lane = e & 63;
    const int c = cb * 16 + (lane & 15);
    const int k0 = kstep * 32 + ((lane >> 4) << 3);
    ushort r[8];
    #pragma unroll
    for (int i = 0; i < 8; ++i) {
        const int k = k0 + i;
        const float v = (k < DF) ? Wa[k * DF + c] : Wb[(k - DF) * DF + c];
        r[i] = f2bf(v);
    }
    uint4 o;
    o.x = r[0] | ((unsigned)r[1] << 16);
    o.y = r[2] | ((unsigned)r[3] << 16);
    o.z = r[4] | ((unsigned)r[5] << 16);
    o.w = r[6] | ((unsigned)r[7] << 16);
    ((uint4*)out)[e] = o;
}

// ---------------- MFMA pool GEMM: out = relu(x @ Wpool + b), bf16 in/out ----------------
__global__ __launch_bounds__(256) void gemm_pool(const ushort* __restrict__ xb,
                                                 const ushort* __restrict__ wf,
                                                 const float* __restrict__ bias,
                                                 ushort* __restrict__ out, int nrows)
{
    __shared__ ushort wl[16384];
    __shared__ float bs[DF];
    const int tid = threadIdx.x;
    {
        const uint4* s = (const uint4*)wf;
        uint4* d = (uint4*)wl;
        #pragma unroll
        for (int i = 0; i < 8; ++i) d[tid + 256 * i] = s[tid + 256 * i];
        if (tid < DF) bs[tid] = bias[tid];
    }
    __syncthreads();

    const int lane = tid & 63;
    const int w = tid >> 6;
    const int row16 = blockIdx.x * 64 + w * 16;
    const int arow = min(row16 + (lane & 15), nrows - 1);
    const ushort* ap = xb + (size_t)arow * DF + ((lane >> 4) << 3);

    f32x4 acc[8];
    #pragma unroll
    for (int cb = 0; cb < 8; ++cb) acc[cb] = (f32x4){0.f, 0.f, 0.f, 0.f};

    #pragma unroll
    for (int ks = 0; ks < 4; ++ks) {
        const short8 a = *(const short8*)(ap + ks * 32);
        #pragma unroll
        for (int cb = 0; cb < 8; ++cb) {
            const short8 b = ((const short8*)wl)[(ks * 8 + cb) * 64 + lane];
            acc[cb] = __builtin_amdgcn_mfma_f32_16x16x32_bf16(a, b, acc[cb], 0, 0, 0);
        }
    }
    __syncthreads();

    ushort* ol = wl;
    #pragma unroll
    for (int cb = 0; cb < 8; ++cb) {
        const int c = (lane & 15) + (cb << 4);
        const float bv = bs[c];
        #pragma unroll
        for (int reg = 0; reg < 4; ++reg) {
            const int m = ((lane >> 4) << 2) + reg;
            ol[(w * 16 + m) * DF + c] = f2bf(fmaxf(acc[cb][reg] + bv, 0.f));
        }
    }
    __syncthreads();

    const int rowbase = blockIdx.x * 64;
    uint4* og = (uint4*)(out + (size_t)rowbase * DF);
    const uint4* olv = (const uint4*)wl;
    #pragma unroll
    for (int i = 0; i < 4; ++i) {
        const int j = tid + 256 * i;
        if (rowbase + (j >> 4) < nrows) og[j] = olv[j];
    }
}

// ---------------- MFMA fused GEMM+LN: out = relu(LN(x@Wself + n@Wneigh + bias)) ----------------
__global__ __launch_bounds__(256) void gemm_fused_ln(const ushort* __restrict__ xb,
                                                     const ushort* __restrict__ nbuf,
                                                     const ushort* __restrict__ wf,
                                                     const float* __restrict__ bias,
                                                     const float* __restrict__ gamma,
                                                     const float* __restrict__ beta,
                                                     ushort* __restrict__ out, int nrows)
{
    __shared__ ushort wl[32768];
    __shared__ float bs[DF], gs[DF], bt[DF];
    const int tid = threadIdx.x;
    {
        const uint4* s = (const uint4*)wf;
        uint4* d = (uint4*)wl;
        #pragma unroll
        for (int i = 0; i < 16; ++i) d[tid + 256 * i] = s[tid + 256 * i];
        if (tid < DF) { bs[tid] = bias[tid]; gs[tid] = gamma[tid]; bt[tid] = beta[tid]; }
    }
    __syncthreads();

    const int lane = tid & 63;
    const int w = tid >> 6;
    const int row16 = blockIdx.x * 64 + w * 16;
    const int arow = min(row16 + (lane & 15), nrows - 1);
    const ushort* apx = xb + (size_t)arow * DF + ((lane >> 4) << 3);
    const ushort* apn = nbuf + (size_t)arow * DF + ((lane >> 4) << 3);

    f32x4 acc[8];
    #pragma unroll
    for (int cb = 0; cb < 8; ++cb) acc[cb] = (f32x4){0.f, 0.f, 0.f, 0.f};

    #pragma unroll
    for (int ks = 0; ks < 8; ++ks) {
        const short8 a = (ks < 4) ? *(const short8*)(apx + ks * 32)
                                  : *(const short8*)(apn + (ks - 4) * 32);
        #pragma unroll
        for (int cb = 0; cb < 8; ++cb) {
            const short8 b = ((const short8*)wl)[(ks * 8 + cb) * 64 + lane];
            acc[cb] = __builtin_amdgcn_mfma_f32_16x16x32_bf16(a, b, acc[cb], 0, 0, 0);
        }
    }

    #pragma unroll
    for (int cb = 0; cb < 8; ++cb) {
        const float bv = bs[(lane & 15) + (cb << 4)];
        #pragma unroll
        for (int reg = 0; reg < 4; ++reg) acc[cb][reg] += bv;
    }
    float mu[4], inv[4];
    #pragma unroll
    for (int reg = 0; reg < 4; ++reg) {
        float s1 = 0.f, s2 = 0.f;
        #pragma unroll
        for (int cb = 0; cb < 8; ++cb) { const float f = acc[cb][reg]; s1 += f; s2 += f * f; }
        #pragma unroll
        for (int m = 1; m < 16; m <<= 1) { s1 += __shfl_xor(s1, m, 64); s2 += __shfl_xor(s2, m, 64); }
        mu[reg] = s1 * (1.f / 128.f);
        inv[reg] = rsqrtf(s2 * (1.f / 128.f) - mu[reg] * mu[reg] + 1e-5f);
    }
    __syncthreads();

    ushort* ol = wl;
    #pragma unroll
    for (int cb = 0; cb < 8; ++cb) {
        const int c = (lane & 15) + (cb << 4);
        const float gv = gs[c], btv = bt[c];
        #pragma unroll
        for (int reg = 0; reg < 4; ++reg) {
            const int m = ((lane >> 4) << 2) + reg;
            const float v = (acc[cb][reg] - mu[reg]) * inv[reg] * gv + btv;
            ol[(w * 16 + m) * DF + c] = f2bf(fmaxf(v, 0.f));
        }
    }
    __syncthreads();

    const int rowbase = blockIdx.x * 64;
    uint4* og = (uint4*)(out + (size_t)rowbase * DF);
    const uint4* olv = (const uint4*)wl;
    #pragma unroll
    for (int i = 0; i < 4; ++i) {
        const int j = tid + 256 * i;
        if (rowbase + (j >> 4) < nrows) og[j] = olv[j];
    }
}

// ---------------- CSR build v2: two-level bucket sort, owner-computes writes ----------------
// Bucket b covers nodes [b*256, b*256+256). NB = ceil(N/256) <= 256.

__global__ __launch_bounds__(256) void bucket_hist(const int* __restrict__ dst,
                                                   int* __restrict__ bhist, int nE)
{
    __shared__ int lh[256];
    lh[threadIdx.x] = 0;
    __syncthreads();
    const int stride = gridDim.x * 256;
    for (int e = blockIdx.x * 256 + threadIdx.x; e < nE; e += stride)
        atomicAdd(&lh[dst[e] >> 8], 1);
    __syncthreads();
    const int v = lh[threadIdx.x];
    if (v) atomicAdd(&bhist[threadIdx.x], v);
}

__global__ __launch_bounds__(256) void bucket_scan(const int* __restrict__ bhist,
                                                   int* __restrict__ bstart,
                                                   int* __restrict__ gcursor, int NB, int nE)
{
    __shared__ int s[256];
    const int t = threadIdx.x;
    const int v = (t < NB) ? bhist[t] : 0;
    s[t] = v;
    __syncthreads();
    for (int off = 1; off < 256; off <<= 1) {
        const int tmp = (t >= off) ? s[t - off] : 0;
        __syncthreads();
        s[t] += tmp;
        __syncthreads();
    }
    const int excl = s[t] - v;
    if (t < NB) { bstart[t] = excl; gcursor[t] = excl; }
    if (t == 0) bstart[NB] = nE;
}

// LDS multisplit: chunk of 2048 edges -> bucket-sorted in LDS -> contiguous burst per bucket.
__global__ __launch_bounds__(256) void bucket_scatter(const int* __restrict__ src,
                                                      const int* __restrict__ dst,
                                                      int* __restrict__ gcursor,
                                                      uint2* __restrict__ bbuf, int nE)
{
    __shared__ int lh[256], lsc[256], gb[256];
    __shared__ uint2 lbuf[SCHUNK];
    const int tid = threadIdx.x;
    const int base = blockIdx.x * SCHUNK;
    const int cnt = min(SCHUNK, nE - base);
    lh[tid] = 0;
    __syncthreads();
    int b[8], pos[8]; unsigned sv[8], dv[8];
    #pragma unroll
    for (int i = 0; i < 8; ++i) {
        const int li = i * 256 + tid;
        if (li < cnt) {
            sv[i] = src[base + li]; dv[i] = dst[base + li];
            b[i] = dv[i] >> 8;
            pos[i] = atomicAdd(&lh[b[i]], 1);
        } else b[i] = -1;
    }
    __syncthreads();
    const int v = lh[tid];
    lsc[tid] = v;
    __syncthreads();
    for (int off = 1; off < 256; off <<= 1) {
        const int tmp = (tid >= off) ? lsc[tid - off] : 0;
        __syncthreads();
        lsc[tid] += tmp;
        __syncthreads();
    }
    const int excl = lsc[tid] - v;
    __syncthreads();
    lsc[tid] = excl;
    if (v > 0) gb[tid] = atomicAdd(&gcursor[tid], v);
    __syncthreads();
    #pragma unroll
    for (int i = 0; i < 8; ++i)
        if (b[i] >= 0) lbuf[lsc[b[i]] + pos[i]] = make_uint2(sv[i], dv[i]);
    __syncthreads();
    for (int j = tid; j < cnt; j += 256) {
        const uint2 p = lbuf[j];
        const int bb = p.y >> 8;
        bbuf[gb[bb] + (j - lsc[bb])] = p;   // contiguous within bucket run
    }
}

// per-bucket degree -> coalesced deg writes (no global atomics)
__global__ __launch_bounds__(256) void bucket_deg(const uint2* __restrict__ bbuf,
                                                  const int* __restrict__ bstart,
                                                  int* __restrict__ deg, int n)
{
    __shared__ int lh[256];
    const int t = threadIdx.x;
    const int b = blockIdx.x;
    lh[t] = 0;
    __syncthreads();
    const int lo = bstart[b], hi = bstart[b + 1];
    for (int j = lo + t; j < hi; j += 256)
        atomicAdd(&lh[bbuf[j].y & 255], 1);
    __syncthreads();
    const int node = (b << 8) + t;
    if (node < n) deg[node] = lh[t];
}

// per-bucket scatter into final csr region (single WG owns its contiguous csr lines)
__global__ __launch_bounds__(256) void bucket_to_csr(const uint2* __restrict__ bbuf,
                                                     const int* __restrict__ bstart,
                                                     const int* __restrict__ start,
                                                     int* __restrict__ csr_src)
{
    __shared__ int lc[256];
    const int t = threadIdx.x;
    const int b = blockIdx.x;
    lc[t] = 0;
    __syncthreads();
    const int lo = bstart[b], hi = bstart[b + 1];
    for (int j = lo + t; j < hi; j += 256) {
        const uint2 p = bbuf[j];
        const int ofs = atomicAdd(&lc[p.y & 255], 1);
        csr_src[start[p.y] + ofs] = p.x;
    }
}

// ---------------- node-level scan (deg -> start) ----------------
__global__ __launch_bounds__(256) void scan_partials(const int* __restrict__ deg,
                                                     int* __restrict__ part, int n)
{
    __shared__ int red[256];
    const int t = threadIdx.x;
    const int base = blockIdx.x * 1024 + t * 4;
    int4 v = make_int4(0, 0, 0, 0);
    if (base + 3 < n) v = *(const int4*)(deg + base);
    else {
        if (base     < n) v.x = deg[base];
        if (base + 1 < n) v.y = deg[base + 1];
        if (base + 2 < n) v.z = deg[base + 2];
        if (base + 3 < n) v.w = deg[base + 3];
    }
    red[t] = v.x + v.y + v.z + v.w;
    __syncthreads();
    for (int off = 128; off > 0; off >>= 1) {
        if (t < off) red[t] += red[t + off];
        __syncthreads();
    }
    if (t == 0) part[blockIdx.x] = red[0];
}

__global__ __launch_bounds__(256) void scan_mid(int* __restrict__ part, int nb)
{
    __shared__ int s[256];
    const int t = threadIdx.x;
    const int orig = (t < nb) ? part[t] : 0;
    s[t] = orig;
    __syncthreads();
    for (int off = 1; off < 256; off <<= 1) {
        const int tmp = (t >= off) ? s[t - off] : 0;
        __syncthreads();
        s[t] += tmp;
        __syncthreads();
    }
    if (t < nb) part[t] = s[t] - orig;
}

__global__ __launch_bounds__(256) void scan_final(const int* __restrict__ deg,
                                                  const int* __restrict__ part,
                                                  int* __restrict__ start,
                                                  int n, int nE)
{
    __shared__ int red[256];
    const int t = threadIdx.x;
    const int base = blockIdx.x * 1024 + t * 4;
    int4 v = make_int4(0, 0, 0, 0);
    if (base + 3 < n) v = *(const int4*)(deg + base);
    else {
        if (base     < n) v.x = deg[base];
        if (base + 1 < n) v.y = deg[base + 1];
        if (base + 2 < n) v.z = deg[base + 2];
        if (base + 3 < n) v.w = deg[base + 3];
    }
    const int s = v.x + v.y + v.z + v.w;
    red[t] = s;
    __syncthreads();
    for (int off = 1; off < 256; off <<= 1) {
        const int tmp = (t >= off) ? red[t - off] : 0;
        __syncthreads();
        red[t] += tmp;
        __syncthreads();
    }
    int excl = red[t] - s + part[blockIdx.x];
    int4 o;
    o.x = excl; o.y = o.x + v.x; o.z = o.y + v.y; o.w = o.z + v.z;
    if (base + 3 < n) {
        *(int4*)(start + base) = o;
    } else {
        if (base     < n) start[base]     = o.x;
        if (base + 1 < n) start[base + 1] = o.y;
        if (base + 2 < n) start[base + 2] = o.z;
        if (base + 3 < n) start[base + 3] = o.w;
    }
    if (blockIdx.x == 0 && t == 0) start[n] = nE;
}

// ---------------- pull max (bf16) ----------------
__global__ __launch_bounds__(256) void pull_max(const ushort* __restrict__ h,
                                                const int* __restrict__ csr_src,
                                                const int* __restrict__ start,
                                                ushort* __restrict__ neigh, int n)
{
    const int lane = threadIdx.x & 63;
    const int wid = threadIdx.x >> 6;
    const int node = blockIdx.x * 4 + wid;
    if (node >= n) return;
    const int s0 = start[node];
    const int s1 = start[node + 1];
    unsigned mlo = 0, mhi = 0;
    for (int base = s0; base < s1; base += 64) {
        const int cnt = min(64, s1 - base);
        const int myidx = (base + lane < s1) ? csr_src[base + lane] : 0;
        int j = 0;
        for (; j + 2 <= cnt; j += 2) {
            const int sa = __shfl(myidx, j, 64);
            const int sb = __shfl(myidx, j + 1, 64);
            const unsigned va = ((const unsigned*)(h + (size_t)sa * DF))[lane];
            const unsigned vb = ((const unsigned*)(h + (size_t)sb * DF))[lane];
            mlo = max(mlo, max(va & 0xffffu, vb & 0xffffu));
            mhi = max(mhi, max(va >> 16, vb >> 16));
        }
        if (j < cnt) {
            const int sa = __shfl(myidx, j, 64);
            const unsigned va = ((const unsigned*)(h + (size_t)sa * DF))[lane];
            mlo = max(mlo, va & 0xffffu);
            mhi = max(mhi, va >> 16);
        }
    }
    ((unsigned*)(neigh + (size_t)node * DF))[lane] = mlo | (mhi << 16);
}

// ---------------- readout ----------------
__global__ __launch_bounds__(128) void colmax(const ushort* __restrict__ x,
                                              unsigned* __restrict__ g, int nrows)
{
    const int c = threadIdx.x;
    float m = 0.f;
    for (int n = blockIdx.x; n < nrows; n += gridDim.x)
        m = fmaxf(m, bf2f(x[(size_t)n * DF + c]));
    atomicMax(g + c, __float_as_uint(m));
}

__global__ __launch_bounds__(128) void head(const float* __restrict__ g,
                                            const float* __restrict__ Wfc1,
                                            const float* __restrict__ bfc1,
                                            const float* __restrict__ Wfc,
                                            const float* __restrict__ bfc,
                                            float* __restrict__ out)
{
    __shared__ float gsh[DF];
    __shared__ float tsh[DF];
    const int t = threadIdx.x;
    gsh[t] = g[t];
    __syncthreads();
    float acc = bfc1[t];
    #pragma unroll 8
    for (int k = 0; k < DF; ++k) acc = fmaf(gsh[k], Wfc1[k * DF + t], acc);
    tsh[t] = acc * Wfc[t];
    __syncthreads();
    if (t == 0) {
        float s = 0.f;
        for (int i = 0; i < DF; ++i) s += tsh[i];
        out[0] = s + bfc[0];
    }
}

extern "C" void kernel_launch(void* const* d_in, const int* in_sizes, int n_in,
                              void* d_out, int out_size, void* d_ws, size_t ws_size,
                              hipStream_t stream) {
    const float* x0     = (const float*)d_in[0];
    const int*   src    = (const int*)d_in[1];
    const int*   dst    = (const int*)d_in[2];
    const float* Wpool0 = (const float*)d_in[3];
    const float* bpool0 = (const float*)d_in[4];
    const float* Wself0 = (const float*)d_in[5];
    const float* Wneigh0= (const float*)d_in[6];
    const float* bias0  = (const float*)d_in[7];
    const float* gamma0 = (const float*)d_in[8];
    const float* beta0  = (const float*)d_in[9];
    const float* Wpool1 = (const float*)d_in[10];
    const float* bpool1 = (const float*)d_in[11];
    const float* Wself1 = (const float*)d_in[12];
    const float* Wneigh1= (const float*)d_in[13];
    const float* bias1  = (const float*)d_in[14];
    const float* gamma1 = (const float*)d_in[15];
    const float* beta1  = (const float*)d_in[16];
    const float* Wfc1   = (const float*)d_in[17];
    const float* bfc1   = (const float*)d_in[18];
    const float* Wfc    = (const float*)d_in[19];
    const float* bfc    = (const float*)d_in[20];

    const int N  = in_sizes[0] / DF;   // 50000
    const int nE = in_sizes[1];        // 800000
    const size_t bufElems = (size_t)N * DF;
    const int NB = (N + 255) >> 8;     // 196 buckets

    ushort* xb   = (ushort*)d_ws;            // 12.8 MB each
    ushort* x1b  = xb + bufElems;
    ushort* hb   = x1b + bufElems;
    ushort* nbuf = hb + bufElems;
    uint2* bbuf  = (uint2*)(nbuf + bufElems); // nE pairs = 6.4 MB
    ushort* wfp0 = (ushort*)(bbuf + nE);
    ushort* wfp1 = wfp0 + 16384;
    ushort* wfc0 = wfp1 + 16384;
    ushort* wfc1 = wfc0 + 32768;
    unsigned* g  = (unsigned*)(wfc1 + 32768);
    int* deg     = (int*)(g + DF);
    int* start   = deg + N;              // N+1
    int* csr_src = start + N + 1;        // nE
    int* part    = csr_src + nE;         // 256
    int* bhist   = part + 256;           // 256
    int* bstart  = bhist + 256;          // 257
    int* gcursor = bstart + 257;         // 256

    const dim3 gP((N + 3) / 4);
    const dim3 gM((N + 63) / 64);
    const int nb_scan = (N + 1023) / 1024;
    const int nSC = (nE + SCHUNK - 1) / SCHUNK;   // 391

    // ---- prep: bf16 input + fragment-ordered weights ----
    convert_bf16<<<(int)((bufElems / 8 + 255) / 256), 256, 0, stream>>>(x0, xb, (int)(bufElems / 8));
    prep_frag<<<8, 256, 0, stream>>>(Wpool0, Wpool0, wfp0, 2048);
    prep_frag<<<8, 256, 0, stream>>>(Wpool1, Wpool1, wfp1, 2048);
    prep_frag<<<16, 256, 0, stream>>>(Wself0, Wneigh0, wfc0, 4096);
    prep_frag<<<16, 256, 0, stream>>>(Wself1, Wneigh1, wfc1, 4096);

    // ---- CSR build v2 (bucketed, owner-computes) ----
    hipMemsetAsync(bhist, 0, 256 * sizeof(int), stream);
    bucket_hist<<<256, 256, 0, stream>>>(dst, bhist, nE);
    bucket_scan<<<1, 256, 0, stream>>>(bhist, bstart, gcursor, NB, nE);
    bucket_scatter<<<nSC, 256, 0, stream>>>(src, dst, gcursor, bbuf, nE);
    bucket_deg<<<NB, 256, 0, stream>>>(bbuf, bstart, deg, N);
    scan_partials<<<nb_scan, 256, 0, stream>>>(deg, part, N);
    scan_mid<<<1, 256, 0, stream>>>(part, nb_scan);
    scan_final<<<nb_scan, 256, 0, stream>>>(deg, part, start, N, nE);
    bucket_to_csr<<<NB, 256, 0, stream>>>(bbuf, bstart, start, csr_src);

    // ---- layer 0 ----
    gemm_pool<<<gM, 256, 0, stream>>>(xb, wfp0, bpool0, hb, N);
    pull_max<<<gP, 256, 0, stream>>>(hb, csr_src, start, nbuf, N);
    gemm_fused_ln<<<gM, 256, 0, stream>>>(xb, nbuf, wfc0, bias0, gamma0, beta0, x1b, N);

    // ---- layer 1 ----
    gemm_pool<<<gM, 256, 0, stream>>>(x1b, wfp1, bpool1, hb, N);
    pull_max<<<gP, 256, 0, stream>>>(hb, csr_src, start, nbuf, N);
    gemm_fused_ln<<<gM, 256, 0, stream>>>(x1b, nbuf, wfc1, bias1, gamma1, beta1, xb, N);  // x2 -> xb

    // ---- readout ----
    hipMemsetAsync(g, 0, DF * sizeof(float), stream);
    colmax<<<512, 128, 0, stream>>>(xb, g, N);
    head<<<1, 128, 0, stream>>>((const float*)g, Wfc1, bfc1, Wfc, bfc, (float*)d_out);
}

// Round 13
// 209.697 us; speedup vs baseline: 6.5137x; 1.1031x over previous
//
#include <hip/hip_runtime.h>

#define DF 128
#define SCHUNK 2048

typedef __attribute__((ext_vector_type(8))) short short8;
typedef __attribute__((ext_vector_type(4))) float f32x4;

__device__ __forceinline__ ushort f2bf(float f) {
    unsigned u = __float_as_uint(f);
    return (ushort)((u + 0x7fffu + ((u >> 16) & 1u)) >> 16);   // RNE
}
__device__ __forceinline__ float bf2f(ushort h) {
    return __uint_as_float(((unsigned)h) << 16);
}

// ---------------- prep: fp32 -> bf16 activation convert ----------------
__global__ __launch_bounds__(256) void convert_bf16(const float* __restrict__ in,
                                                    ushort* __restrict__ out, int n8)
{
    const int i = blockIdx.x * 256 + threadIdx.x;
    if (i >= n8) return;
    const float4* p = (const float4*)(in + (size_t)i * 8);
    float4 a = p[0], b = p[1];
    uint4 o;
    o.x = f2bf(a.x) | ((unsigned)f2bf(a.y) << 16);
    o.y = f2bf(a.z) | ((unsigned)f2bf(a.w) << 16);
    o.z = f2bf(b.x) | ((unsigned)f2bf(b.y) << 16);
    o.w = f2bf(b.z) | ((unsigned)f2bf(b.w) << 16);
    ((uint4*)out)[i] = o;
}

// ---------------- prep: weights -> MFMA-fragment-ordered bf16 ----------------
__global__ __launch_bounds__(256) void prep_frag(const float* __restrict__ Wa,
                                                 const float* __restrict__ Wb,
                                                 ushort* __restrict__ out, int nent)
{
    const int e = blockIdx.x * 256 + threadIdx.x;
    if (e >= nent) return;
    const int kstep = e >> 9;
    const int cb = (e >> 6) & 7;
    const int lane = e & 63;
    const int c = cb * 16 + (lane & 15);
    const int k0 = kstep * 32 + ((lane >> 4) << 3);
    ushort r[8];
    #pragma unroll
    for (int i = 0; i < 8; ++i) {
        const int k = k0 + i;
        const float v = (k < DF) ? Wa[k * DF + c] : Wb[(k - DF) * DF + c];
        r[i] = f2bf(v);
    }
    uint4 o;
    o.x = r[0] | ((unsigned)r[1] << 16);
    o.y = r[2] | ((unsigned)r[3] << 16);
    o.z = r[4] | ((unsigned)r[5] << 16);
    o.w = r[6] | ((unsigned)r[7] << 16);
    ((uint4*)out)[e] = o;
}

// ---------------- MFMA pool GEMM: out = relu(x @ Wpool + b), 128 rows/block ----------------
// 4 waves x 32 rows (2 row-tiles of 16). Weights 32KB LDS, reused as out staging.
__global__ __launch_bounds__(256) void gemm_pool(const ushort* __restrict__ xb,
                                                 const ushort* __restrict__ wf,
                                                 const float* __restrict__ bias,
                                                 ushort* __restrict__ out, int nrows)
{
    __shared__ ushort wl[16384];
    __shared__ float bs[DF];
    const int tid = threadIdx.x;
    {
        const uint4* s = (const uint4*)wf;
        uint4* d = (uint4*)wl;
        #pragma unroll
        for (int i = 0; i < 8; ++i) d[tid + 256 * i] = s[tid + 256 * i];
        if (tid < DF) bs[tid] = bias[tid];
    }
    __syncthreads();

    const int lane = tid & 63;
    const int w = tid >> 6;
    const int rb = blockIdx.x * 128 + w * 32;
    const int ar0 = min(rb + (lane & 15), nrows - 1);
    const int ar1 = min(rb + 16 + (lane & 15), nrows - 1);
    const ushort* ap0 = xb + (size_t)ar0 * DF + ((lane >> 4) << 3);
    const ushort* ap1 = xb + (size_t)ar1 * DF + ((lane >> 4) << 3);

    f32x4 acc[2][8];
    #pragma unroll
    for (int tt = 0; tt < 2; ++tt)
        #pragma unroll
        for (int cb = 0; cb < 8; ++cb) acc[tt][cb] = (f32x4){0.f, 0.f, 0.f, 0.f};

    #pragma unroll
    for (int ks = 0; ks < 4; ++ks) {
        const short8 a0 = *(const short8*)(ap0 + ks * 32);
        const short8 a1 = *(const short8*)(ap1 + ks * 32);
        #pragma unroll
        for (int cb = 0; cb < 8; ++cb) {
            const short8 b = ((const short8*)wl)[(ks * 8 + cb) * 64 + lane];
            acc[0][cb] = __builtin_amdgcn_mfma_f32_16x16x32_bf16(a0, b, acc[0][cb], 0, 0, 0);
            acc[1][cb] = __builtin_amdgcn_mfma_f32_16x16x32_bf16(a1, b, acc[1][cb], 0, 0, 0);
        }
    }
    __syncthreads();   // wl dead as weights; reuse as out staging (128*128*2B = 32KB)

    ushort* ol = wl;
    #pragma unroll
    for (int tt = 0; tt < 2; ++tt)
        #pragma unroll
        for (int cb = 0; cb < 8; ++cb) {
            const int c = (lane & 15) + (cb << 4);
            const float bv = bs[c];
            #pragma unroll
            for (int reg = 0; reg < 4; ++reg) {
                const int m = ((lane >> 4) << 2) + reg;
                ol[(w * 32 + tt * 16 + m) * DF + c] = f2bf(fmaxf(acc[tt][cb][reg] + bv, 0.f));
            }
        }
    __syncthreads();

    const int rowbase = blockIdx.x * 128;
    uint4* og = (uint4*)(out + (size_t)rowbase * DF);
    const uint4* olv = (const uint4*)wl;
    #pragma unroll
    for (int i = 0; i < 8; ++i) {
        const int j = tid + 256 * i;          // 2048 uint4 = 128 rows * 16
        if (rowbase + (j >> 4) < nrows) og[j] = olv[j];
    }
}

// ---------------- MFMA fused GEMM+LN: out = relu(LN(x@Wself + n@Wneigh + bias)), 128 rows/block ----------------
__global__ __launch_bounds__(256) void gemm_fused_ln(const ushort* __restrict__ xb,
                                                     const ushort* __restrict__ nbuf,
                                                     const ushort* __restrict__ wf,
                                                     const float* __restrict__ bias,
                                                     const float* __restrict__ gamma,
                                                     const float* __restrict__ beta,
                                                     ushort* __restrict__ out, int nrows)
{
    __shared__ ushort wl[32768];
    __shared__ float bs[DF], gs[DF], bt[DF];
    const int tid = threadIdx.x;
    {
        const uint4* s = (const uint4*)wf;
        uint4* d = (uint4*)wl;
        #pragma unroll
        for (int i = 0; i < 16; ++i) d[tid + 256 * i] = s[tid + 256 * i];
        if (tid < DF) { bs[tid] = bias[tid]; gs[tid] = gamma[tid]; bt[tid] = beta[tid]; }
    }
    __syncthreads();

    const int lane = tid & 63;
    const int w = tid >> 6;
    const int rb = blockIdx.x * 128 + w * 32;
    const int ar0 = min(rb + (lane & 15), nrows - 1);
    const int ar1 = min(rb + 16 + (lane & 15), nrows - 1);
    const int ko = (lane >> 4) << 3;
    const ushort* apx0 = xb + (size_t)ar0 * DF + ko;
    const ushort* apx1 = xb + (size_t)ar1 * DF + ko;
    const ushort* apn0 = nbuf + (size_t)ar0 * DF + ko;
    const ushort* apn1 = nbuf + (size_t)ar1 * DF + ko;

    f32x4 acc[2][8];
    #pragma unroll
    for (int tt = 0; tt < 2; ++tt)
        #pragma unroll
        for (int cb = 0; cb < 8; ++cb) acc[tt][cb] = (f32x4){0.f, 0.f, 0.f, 0.f};

    #pragma unroll
    for (int ks = 0; ks < 8; ++ks) {
        const short8 a0 = (ks < 4) ? *(const short8*)(apx0 + ks * 32)
                                   : *(const short8*)(apn0 + (ks - 4) * 32);
        const short8 a1 = (ks < 4) ? *(const short8*)(apx1 + ks * 32)
                                   : *(const short8*)(apn1 + (ks - 4) * 32);
        #pragma unroll
        for (int cb = 0; cb < 8; ++cb) {
            const short8 b = ((const short8*)wl)[(ks * 8 + cb) * 64 + lane];
            acc[0][cb] = __builtin_amdgcn_mfma_f32_16x16x32_bf16(a0, b, acc[0][cb], 0, 0, 0);
            acc[1][cb] = __builtin_amdgcn_mfma_f32_16x16x32_bf16(a1, b, acc[1][cb], 0, 0, 0);
        }
    }

    float mu[2][4], inv[2][4];
    #pragma unroll
    for (int tt = 0; tt < 2; ++tt) {
        #pragma unroll
        for (int cb = 0; cb < 8; ++cb) {
            const float bv = bs[(lane & 15) + (cb << 4)];
            #pragma unroll
            for (int reg = 0; reg < 4; ++reg) acc[tt][cb][reg] += bv;
        }
        #pragma unroll
        for (int reg = 0; reg < 4; ++reg) {
            float s1 = 0.f, s2 = 0.f;
            #pragma unroll
            for (int cb = 0; cb < 8; ++cb) { const float f = acc[tt][cb][reg]; s1 += f; s2 += f * f; }
            #pragma unroll
            for (int m = 1; m < 16; m <<= 1) { s1 += __shfl_xor(s1, m, 64); s2 += __shfl_xor(s2, m, 64); }
            mu[tt][reg] = s1 * (1.f / 128.f);
            inv[tt][reg] = rsqrtf(s2 * (1.f / 128.f) - mu[tt][reg] * mu[tt][reg] + 1e-5f);
        }
    }
    __syncthreads();   // wl weights dead; reuse as out staging

    ushort* ol = wl;
    #pragma unroll
    for (int tt = 0; tt < 2; ++tt)
        #pragma unroll
        for (int cb = 0; cb < 8; ++cb) {
            const int c = (lane & 15) + (cb << 4);
            const float gv = gs[c], btv = bt[c];
            #pragma unroll
            for (int reg = 0; reg < 4; ++reg) {
                const int m = ((lane >> 4) << 2) + reg;
                const float v = (acc[tt][cb][reg] - mu[tt][reg]) * inv[tt][reg] * gv + btv;
                ol[(w * 32 + tt * 16 + m) * DF + c] = f2bf(fmaxf(v, 0.f));
            }
        }
    __syncthreads();

    const int rowbase = blockIdx.x * 128;
    uint4* og = (uint4*)(out + (size_t)rowbase * DF);
    const uint4* olv = (const uint4*)wl;
    #pragma unroll
    for (int i = 0; i < 8; ++i) {
        const int j = tid + 256 * i;
        if (rowbase + (j >> 4) < nrows) og[j] = olv[j];
    }
}

// ---------------- CSR build: bucket sort + single finish kernel ----------------
// Bucket b covers nodes [b*256, b*256+256).

__global__ __launch_bounds__(256) void bucket_hist(const int* __restrict__ dst,
                                                   int* __restrict__ bhist, int nE)
{
    __shared__ int lh[256];
    lh[threadIdx.x] = 0;
    __syncthreads();
    const int stride = gridDim.x * 256;
    for (int e = blockIdx.x * 256 + threadIdx.x; e < nE; e += stride)
        atomicAdd(&lh[dst[e] >> 8], 1);
    __syncthreads();
    const int v = lh[threadIdx.x];
    if (v) atomicAdd(&bhist[threadIdx.x], v);
}

__global__ __launch_bounds__(256) void bucket_scan(const int* __restrict__ bhist,
                                                   int* __restrict__ bstart,
                                                   int* __restrict__ gcursor, int NB, int nE)
{
    __shared__ int s[256];
    const int t = threadIdx.x;
    const int v = (t < NB) ? bhist[t] : 0;
    s[t] = v;
    __syncthreads();
    for (int off = 1; off < 256; off <<= 1) {
        const int tmp = (t >= off) ? s[t - off] : 0;
        __syncthreads();
        s[t] += tmp;
        __syncthreads();
    }
    const int excl = s[t] - v;
    if (t < NB) { bstart[t] = excl; gcursor[t] = excl; }
    if (t == 0) bstart[NB] = nE;
}

// LDS multisplit: chunk of 2048 edges -> bucket-sorted in LDS -> contiguous burst per bucket.
__global__ __launch_bounds__(256) void bucket_scatter(const int* __restrict__ src,
                                                      const int* __restrict__ dst,
                                                      int* __restrict__ gcursor,
                                                      uint2* __restrict__ bbuf, int nE)
{
    __shared__ int lh[256], lsc[256], gb[256];
    __shared__ uint2 lbuf[SCHUNK];
    const int tid = threadIdx.x;
    const int base = blockIdx.x * SCHUNK;
    const int cnt = min(SCHUNK, nE - base);
    lh[tid] = 0;
    __syncthreads();
    int b[8], pos[8]; unsigned sv[8], dv[8];
    #pragma unroll
    for (int i = 0; i < 8; ++i) {
        const int li = i * 256 + tid;
        if (li < cnt) {
            sv[i] = src[base + li]; dv[i] = dst[base + li];
            b[i] = dv[i] >> 8;
            pos[i] = atomicAdd(&lh[b[i]], 1);
        } else b[i] = -1;
    }
    __syncthreads();
    const int v = lh[tid];
    lsc[tid] = v;
    __syncthreads();
    for (int off = 1; off < 256; off <<= 1) {
        const int tmp = (tid >= off) ? lsc[tid - off] : 0;
        __syncthreads();
        lsc[tid] += tmp;
        __syncthreads();
    }
    const int excl = lsc[tid] - v;
    __syncthreads();
    lsc[tid] = excl;
    if (v > 0) gb[tid] = atomicAdd(&gcursor[tid], v);
    __syncthreads();
    #pragma unroll
    for (int i = 0; i < 8; ++i)
        if (b[i] >= 0) lbuf[lsc[b[i]] + pos[i]] = make_uint2(sv[i], dv[i]);
    __syncthreads();
    for (int j = tid; j < cnt; j += 256) {
        const uint2 p = lbuf[j];
        const int bb = p.y >> 8;
        bbuf[gb[bb] + (j - lsc[bb])] = p;
    }
}

// per-bucket: LDS hist -> LDS scan (+bstart[b]) -> write start -> scatter csr. One kernel.
__global__ __launch_bounds__(256) void bucket_finish(const uint2* __restrict__ bbuf,
                                                     const int* __restrict__ bstart,
                                                     int* __restrict__ start,
                                                     int* __restrict__ csr_src,
                                                     int n, int nE)
{
    __shared__ int lh[256], ns[256], lc[256];
    const int t = threadIdx.x;
    const int b = blockIdx.x;
    lh[t] = 0; lc[t] = 0;
    __syncthreads();
    const int lo = bstart[b], hi = bstart[b + 1];
    for (int j = lo + t; j < hi; j += 256)
        atomicAdd(&lh[bbuf[j].y & 255], 1);
    __syncthreads();
    const int v = lh[t];
    ns[t] = v;
    __syncthreads();
    for (int off = 1; off < 256; off <<= 1) {
        const int tmp = (t >= off) ? ns[t - off] : 0;
        __syncthreads();
        ns[t] += tmp;
        __syncthreads();
    }
    const int excl = ns[t] - v;
    ns[t] = excl + lo;               // absolute csr start of node (b<<8)+t
    const int node = (b << 8) + t;
    if (node < n) start[node] = ns[t];
    if (b == gridDim.x - 1 && t == 0) start[n] = nE;
    __syncthreads();
    for (int j = lo + t; j < hi; j += 256) {
        const uint2 p = bbuf[j];
        const int loc = p.y & 255;
        const int ofs = atomicAdd(&lc[loc], 1);
        csr_src[ns[loc] + ofs] = p.x;
    }
}

// ---------------- pull max (bf16), 4-way ILP ----------------
__global__ __launch_bounds__(256) void pull_max(const ushort* __restrict__ h,
                                                const int* __restrict__ csr_src,
                                                const int* __restrict__ start,
                                                ushort* __restrict__ neigh, int n)
{
    const int lane = threadIdx.x & 63;
    const int wid = threadIdx.x >> 6;
    const int node = blockIdx.x * 4 + wid;
    if (node >= n) return;
    const int s0 = start[node];
    const int s1 = start[node + 1];
    unsigned mlo = 0, mhi = 0;
    for (int base = s0; base < s1; base += 64) {
        const int cnt = min(64, s1 - base);
        const int myidx = (base + lane < s1) ? csr_src[base + lane] : 0;
        int j = 0;
        for (; j + 4 <= cnt; j += 4) {
            const int sa = __shfl(myidx, j, 64);
            const int sb = __shfl(myidx, j + 1, 64);
            const int sc = __shfl(myidx, j + 2, 64);
            const int sd = __shfl(myidx, j + 3, 64);
            const unsigned va = ((const unsigned*)(h + (size_t)sa * DF))[lane];
            const unsigned vb = ((const unsigned*)(h + (size_t)sb * DF))[lane];
            const unsigned vc = ((const unsigned*)(h + (size_t)sc * DF))[lane];
            const unsigned vd = ((const unsigned*)(h + (size_t)sd * DF))[lane];
            mlo = max(mlo, max(max(va & 0xffffu, vb & 0xffffu), max(vc & 0xffffu, vd & 0xffffu)));
            mhi = max(mhi, max(max(va >> 16, vb >> 16), max(vc >> 16, vd >> 16)));
        }
        for (; j < cnt; ++j) {
            const int sa = __shfl(myidx, j, 64);
            const unsigned va = ((const unsigned*)(h + (size_t)sa * DF))[lane];
            mlo = max(mlo, va & 0xffffu);
            mhi = max(mhi, va >> 16);
        }
    }
    ((unsigned*)(neigh + (size_t)node * DF))[lane] = mlo | (mhi << 16);
}

// ---------------- readout ----------------
__global__ __launch_bounds__(128) void colmax(const ushort* __restrict__ x,
                                              unsigned* __restrict__ g, int nrows)
{
    const int c = threadIdx.x;
    float m = 0.f;
    for (int n = blockIdx.x; n < nrows; n += gridDim.x)
        m = fmaxf(m, bf2f(x[(size_t)n * DF + c]));
    atomicMax(g + c, __float_as_uint(m));
}

__global__ __launch_bounds__(128) void head(const float* __restrict__ g,
                                            const float* __restrict__ Wfc1,
                                            const float* __restrict__ bfc1,
                                            const float* __restrict__ Wfc,
                                            const float* __restrict__ bfc,
                                            float* __restrict__ out)
{
    __shared__ float gsh[DF];
    __shared__ float tsh[DF];
    const int t = threadIdx.x;
    gsh[t] = g[t];
    __syncthreads();
    float acc = bfc1[t];
    #pragma unroll 8
    for (int k = 0; k < DF; ++k) acc = fmaf(gsh[k], Wfc1[k * DF + t], acc);
    tsh[t] = acc * Wfc[t];
    __syncthreads();
    if (t == 0) {
        float s = 0.f;
        for (int i = 0; i < DF; ++i) s += tsh[i];
        out[0] = s + bfc[0];
    }
}

extern "C" void kernel_launch(void* const* d_in, const int* in_sizes, int n_in,
                              void* d_out, int out_size, void* d_ws, size_t ws_size,
                              hipStream_t stream) {
    const float* x0     = (const float*)d_in[0];
    const int*   src    = (const int*)d_in[1];
    const int*   dst    = (const int*)d_in[2];
    const float* Wpool0 = (const float*)d_in[3];
    const float* bpool0 = (const float*)d_in[4];
    const float* Wself0 = (const float*)d_in[5];
    const float* Wneigh0= (const float*)d_in[6];
    const float* bias0  = (const float*)d_in[7];
    const float* gamma0 = (const float*)d_in[8];
    const float* beta0  = (const float*)d_in[9];
    const float* Wpool1 = (const float*)d_in[10];
    const float* bpool1 = (const float*)d_in[11];
    const float* Wself1 = (const float*)d_in[12];
    const float* Wneigh1= (const float*)d_in[13];
    const float* bias1  = (const float*)d_in[14];
    const float* gamma1 = (const float*)d_in[15];
    const float* beta1  = (const float*)d_in[16];
    const float* Wfc1   = (const float*)d_in[17];
    const float* bfc1   = (const float*)d_in[18];
    const float* Wfc    = (const float*)d_in[19];
    const float* bfc    = (const float*)d_in[20];

    const int N  = in_sizes[0] / DF;   // 50000
    const int nE = in_sizes[1];        // 800000
    const size_t bufElems = (size_t)N * DF;
    const int NB = (N + 255) >> 8;     // 196 buckets

    ushort* xb   = (ushort*)d_ws;            // 12.8 MB each
    ushort* x1b  = xb + bufElems;
    ushort* hb   = x1b + bufElems;
    ushort* nbuf = hb + bufElems;
    uint2* bbuf  = (uint2*)(nbuf + bufElems); // nE pairs = 6.4 MB
    ushort* wfp0 = (ushort*)(bbuf + nE);
    ushort* wfp1 = wfp0 + 16384;
    ushort* wfc0 = wfp1 + 16384;
    ushort* wfc1 = wfc0 + 32768;
    unsigned* g  = (unsigned*)(wfc1 + 32768);
    int* start   = (int*)(g + DF);       // N+1
    int* csr_src = start + N + 1;        // nE
    int* bhist   = csr_src + nE;         // 256
    int* bstart  = bhist + 256;          // 257
    int* gcursor = bstart + 257;         // 256

    const dim3 gP((N + 3) / 4);
    const dim3 gM((N + 127) / 128);      // 391 MFMA-GEMM blocks
    const int nSC = (nE + SCHUNK - 1) / SCHUNK;   // 391

    // ---- prep: bf16 input + fragment-ordered weights ----
    convert_bf16<<<(int)((bufElems / 8 + 255) / 256), 256, 0, stream>>>(x0, xb, (int)(bufElems / 8));
    prep_frag<<<8, 256, 0, stream>>>(Wpool0, Wpool0, wfp0, 2048);
    prep_frag<<<8, 256, 0, stream>>>(Wpool1, Wpool1, wfp1, 2048);
    prep_frag<<<16, 256, 0, stream>>>(Wself0, Wneigh0, wfc0, 4096);
    prep_frag<<<16, 256, 0, stream>>>(Wself1, Wneigh1, wfc1, 4096);

    // ---- CSR build (bucketed, owner-computes) ----
    hipMemsetAsync(bhist, 0, 256 * sizeof(int), stream);
    bucket_hist<<<256, 256, 0, stream>>>(dst, bhist, nE);
    bucket_scan<<<1, 256, 0, stream>>>(bhist, bstart, gcursor, NB, nE);
    bucket_scatter<<<nSC, 256, 0, stream>>>(src, dst, gcursor, bbuf, nE);
    bucket_finish<<<NB, 256, 0, stream>>>(bbuf, bstart, start, csr_src, N, nE);

    // ---- layer 0 ----
    gemm_pool<<<gM, 256, 0, stream>>>(xb, wfp0, bpool0, hb, N);
    pull_max<<<gP, 256, 0, stream>>>(hb, csr_src, start, nbuf, N);
    gemm_fused_ln<<<gM, 256, 0, stream>>>(xb, nbuf, wfc0, bias0, gamma0, beta0, x1b, N);

    // ---- layer 1 ----
    gemm_pool<<<gM, 256, 0, stream>>>(x1b, wfp1, bpool1, hb, N);
    pull_max<<<gP, 256, 0, stream>>>(hb, csr_src, start, nbuf, N);
    gemm_fused_ln<<<gM, 256, 0, stream>>>(x1b, nbuf, wfc1, bias1, gamma1, beta1, xb, N);  // x2 -> xb

    // ---- readout ----
    hipMemsetAsync(g, 0, DF * sizeof(float), stream);
    colmax<<<512, 128, 0, stream>>>(xb, g, N);
    head<<<1, 128, 0, stream>>>((const float*)g, Wfc1, bfc1, Wfc, bfc, (float*)d_out);
}

// Round 14
// 195.994 us; speedup vs baseline: 6.9691x; 1.0699x over previous
//
#include <hip/hip_runtime.h>

#define DF 128
#define SCHUNK 2048

typedef __attribute__((ext_vector_type(8))) short short8;
typedef __attribute__((ext_vector_type(4))) float f32x4;

__device__ __forceinline__ ushort f2bf(float f) {
    unsigned u = __float_as_uint(f);
    return (ushort)((u + 0x7fffu + ((u >> 16) & 1u)) >> 16);   // RNE
}
__device__ __forceinline__ float bf2f(ushort h) {
    return __uint_as_float(((unsigned)h) << 16);
}
// load 8 fp32, convert to 8 bf16 (RNE) in-register -> MFMA A-fragment
__device__ __forceinline__ short8 ld_a_f32(const float* p) {
    const float4 u = ((const float4*)p)[0];
    const float4 v = ((const float4*)p)[1];
    short8 r;
    r[0] = (short)f2bf(u.x); r[1] = (short)f2bf(u.y);
    r[2] = (short)f2bf(u.z); r[3] = (short)f2bf(u.w);
    r[4] = (short)f2bf(v.x); r[5] = (short)f2bf(v.y);
    r[6] = (short)f2bf(v.z); r[7] = (short)f2bf(v.w);
    return r;
}

// ---------------- prep_all: all 4 weight-fragment buffers + zero bhist/g, one kernel ----------------
// entries: [0,2048) wfp0(Wpool0), [2048,4096) wfp1(Wpool1), [4096,8192) wfc0(Wself0|Wneigh0),
// [8192,12288) wfc1(Wself1|Wneigh1). Block 48: zero bhist(256) + g(128).
__global__ __launch_bounds__(256) void prep_all(const float* __restrict__ Wpool0,
                                                const float* __restrict__ Wpool1,
                                                const float* __restrict__ Wself0,
                                                const float* __restrict__ Wneigh0,
                                                const float* __restrict__ Wself1,
                                                const float* __restrict__ Wneigh1,
                                                ushort* __restrict__ wfp0,
                                                ushort* __restrict__ wfp1,
                                                ushort* __restrict__ wfc0,
                                                ushort* __restrict__ wfc1,
                                                int* __restrict__ bhist,
                                                unsigned* __restrict__ g)
{
    const int tid = threadIdx.x;
    if (blockIdx.x == 48) {
        bhist[tid] = 0;
        if (tid < DF) g[tid] = 0;
        return;
    }
    const int e = blockIdx.x * 256 + tid;
    const float *Wa, *Wb; ushort* out; int le;
    if (e < 2048)      { Wa = Wpool0; Wb = Wpool0;  out = wfp0; le = e; }
    else if (e < 4096) { Wa = Wpool1; Wb = Wpool1;  out = wfp1; le = e - 2048; }
    else if (e < 8192) { Wa = Wself0; Wb = Wneigh0; out = wfc0; le = e - 4096; }
    else               { Wa = Wself1; Wb = Wneigh1; out = wfc1; le = e - 8192; }
    const int kstep = le >> 9;
    const int cb = (le >> 6) & 7;
    const int lane = le & 63;
    const int c = cb * 16 + (lane & 15);
    const int k0 = kstep * 32 + ((lane >> 4) << 3);
    ushort r[8];
    #pragma unroll
    for (int i = 0; i < 8; ++i) {
        const int k = k0 + i;
        const float v = (k < DF) ? Wa[k * DF + c] : Wb[(k - DF) * DF + c];
        r[i] = f2bf(v);
    }
    uint4 o;
    o.x = r[0] | ((unsigned)r[1] << 16);
    o.y = r[2] | ((unsigned)r[3] << 16);
    o.z = r[4] | ((unsigned)r[5] << 16);
    o.w = r[6] | ((unsigned)r[7] << 16);
    ((uint4*)out)[le] = o;
}

// ---------------- MFMA pool GEMM: out = relu(x @ Wpool + b), 128 rows/block ----------------
// AF32: A-operand from fp32 (in-register RNE convert) vs bf16.
template<int AF32>
__global__ __launch_bounds__(256) void gemm_pool(const ushort* __restrict__ xb,
                                                 const float* __restrict__ xf,
                                                 const ushort* __restrict__ wf,
                                                 const float* __restrict__ bias,
                                                 ushort* __restrict__ out, int nrows)
{
    __shared__ ushort wl[16384];
    __shared__ float bs[DF];
    const int tid = threadIdx.x;
    {
        const uint4* s = (const uint4*)wf;
        uint4* d = (uint4*)wl;
        #pragma unroll
        for (int i = 0; i < 8; ++i) d[tid + 256 * i] = s[tid + 256 * i];
        if (tid < DF) bs[tid] = bias[tid];
    }
    __syncthreads();

    const int lane = tid & 63;
    const int w = tid >> 6;
    const int rb = blockIdx.x * 128 + w * 32;
    const int ar0 = min(rb + (lane & 15), nrows - 1);
    const int ar1 = min(rb + 16 + (lane & 15), nrows - 1);
    const int ko = (lane >> 4) << 3;

    f32x4 acc[2][8];
    #pragma unroll
    for (int tt = 0; tt < 2; ++tt)
        #pragma unroll
        for (int cb = 0; cb < 8; ++cb) acc[tt][cb] = (f32x4){0.f, 0.f, 0.f, 0.f};

    #pragma unroll
    for (int ks = 0; ks < 4; ++ks) {
        short8 a0, a1;
        if (AF32) {
            a0 = ld_a_f32(xf + (size_t)ar0 * DF + ko + ks * 32);
            a1 = ld_a_f32(xf + (size_t)ar1 * DF + ko + ks * 32);
        } else {
            a0 = *(const short8*)(xb + (size_t)ar0 * DF + ko + ks * 32);
            a1 = *(const short8*)(xb + (size_t)ar1 * DF + ko + ks * 32);
        }
        #pragma unroll
        for (int cb = 0; cb < 8; ++cb) {
            const short8 b = ((const short8*)wl)[(ks * 8 + cb) * 64 + lane];
            acc[0][cb] = __builtin_amdgcn_mfma_f32_16x16x32_bf16(a0, b, acc[0][cb], 0, 0, 0);
            acc[1][cb] = __builtin_amdgcn_mfma_f32_16x16x32_bf16(a1, b, acc[1][cb], 0, 0, 0);
        }
    }
    __syncthreads();   // wl dead as weights; reuse as out staging (32KB)

    ushort* ol = wl;
    #pragma unroll
    for (int tt = 0; tt < 2; ++tt)
        #pragma unroll
        for (int cb = 0; cb < 8; ++cb) {
            const int c = (lane & 15) + (cb << 4);
            const float bv = bs[c];
            #pragma unroll
            for (int reg = 0; reg < 4; ++reg) {
                const int m = ((lane >> 4) << 2) + reg;
                ol[(w * 32 + tt * 16 + m) * DF + c] = f2bf(fmaxf(acc[tt][cb][reg] + bv, 0.f));
            }
        }
    __syncthreads();

    const int rowbase = blockIdx.x * 128;
    uint4* og = (uint4*)(out + (size_t)rowbase * DF);
    const uint4* olv = (const uint4*)wl;
    #pragma unroll
    for (int i = 0; i < 8; ++i) {
        const int j = tid + 256 * i;
        if (rowbase + (j >> 4) < nrows) og[j] = olv[j];
    }
}

// ---------------- MFMA fused GEMM+LN: out = relu(LN(x@Wself + n@Wneigh + bias)), 128 rows/block ----------------
template<int AF32>
__global__ __launch_bounds__(256) void gemm_fused_ln(const ushort* __restrict__ xb,
                                                     const float* __restrict__ xf,
                                                     const ushort* __restrict__ nbuf,
                                                     const ushort* __restrict__ wf,
                                                     const float* __restrict__ bias,
                                                     const float* __restrict__ gamma,
                                                     const float* __restrict__ beta,
                                                     ushort* __restrict__ out, int nrows)
{
    __shared__ ushort wl[32768];
    __shared__ float bs[DF], gs[DF], bt[DF];
    const int tid = threadIdx.x;
    {
        const uint4* s = (const uint4*)wf;
        uint4* d = (uint4*)wl;
        #pragma unroll
        for (int i = 0; i < 16; ++i) d[tid + 256 * i] = s[tid + 256 * i];
        if (tid < DF) { bs[tid] = bias[tid]; gs[tid] = gamma[tid]; bt[tid] = beta[tid]; }
    }
    __syncthreads();

    const int lane = tid & 63;
    const int w = tid >> 6;
    const int rb = blockIdx.x * 128 + w * 32;
    const int ar0 = min(rb + (lane & 15), nrows - 1);
    const int ar1 = min(rb + 16 + (lane & 15), nrows - 1);
    const int ko = (lane >> 4) << 3;
    const ushort* apn0 = nbuf + (size_t)ar0 * DF + ko;
    const ushort* apn1 = nbuf + (size_t)ar1 * DF + ko;

    f32x4 acc[2][8];
    #pragma unroll
    for (int tt = 0; tt < 2; ++tt)
        #pragma unroll
        for (int cb = 0; cb < 8; ++cb) acc[tt][cb] = (f32x4){0.f, 0.f, 0.f, 0.f};

    #pragma unroll
    for (int ks = 0; ks < 8; ++ks) {
        short8 a0, a1;
        if (ks < 4) {
            if (AF32) {
                a0 = ld_a_f32(xf + (size_t)ar0 * DF + ko + ks * 32);
                a1 = ld_a_f32(xf + (size_t)ar1 * DF + ko + ks * 32);
            } else {
                a0 = *(const short8*)(xb + (size_t)ar0 * DF + ko + ks * 32);
                a1 = *(const short8*)(xb + (size_t)ar1 * DF + ko + ks * 32);
            }
        } else {
            a0 = *(const short8*)(apn0 + (ks - 4) * 32);
            a1 = *(const short8*)(apn1 + (ks - 4) * 32);
        }
        #pragma unroll
        for (int cb = 0; cb < 8; ++cb) {
            const short8 b = ((const short8*)wl)[(ks * 8 + cb) * 64 + lane];
            acc[0][cb] = __builtin_amdgcn_mfma_f32_16x16x32_bf16(a0, b, acc[0][cb], 0, 0, 0);
            acc[1][cb] = __builtin_amdgcn_mfma_f32_16x16x32_bf16(a1, b, acc[1][cb], 0, 0, 0);
        }
    }

    float mu[2][4], inv[2][4];
    #pragma unroll
    for (int tt = 0; tt < 2; ++tt) {
        #pragma unroll
        for (int cb = 0; cb < 8; ++cb) {
            const float bv = bs[(lane & 15) + (cb << 4)];
            #pragma unroll
            for (int reg = 0; reg < 4; ++reg) acc[tt][cb][reg] += bv;
        }
        #pragma unroll
        for (int reg = 0; reg < 4; ++reg) {
            float s1 = 0.f, s2 = 0.f;
            #pragma unroll
            for (int cb = 0; cb < 8; ++cb) { const float f = acc[tt][cb][reg]; s1 += f; s2 += f * f; }
            #pragma unroll
            for (int m = 1; m < 16; m <<= 1) { s1 += __shfl_xor(s1, m, 64); s2 += __shfl_xor(s2, m, 64); }
            mu[tt][reg] = s1 * (1.f / 128.f);
            inv[tt][reg] = rsqrtf(s2 * (1.f / 128.f) - mu[tt][reg] * mu[tt][reg] + 1e-5f);
        }
    }
    __syncthreads();   // wl weights dead; reuse as out staging

    ushort* ol = wl;
    #pragma unroll
    for (int tt = 0; tt < 2; ++tt)
        #pragma unroll
        for (int cb = 0; cb < 8; ++cb) {
            const int c = (lane & 15) + (cb << 4);
            const float gv = gs[c], btv = bt[c];
            #pragma unroll
            for (int reg = 0; reg < 4; ++reg) {
                const int m = ((lane >> 4) << 2) + reg;
                const float v = (acc[tt][cb][reg] - mu[tt][reg]) * inv[tt][reg] * gv + btv;
                ol[(w * 32 + tt * 16 + m) * DF + c] = f2bf(fmaxf(v, 0.f));
            }
        }
    __syncthreads();

    const int rowbase = blockIdx.x * 128;
    uint4* og = (uint4*)(out + (size_t)rowbase * DF);
    const uint4* olv = (const uint4*)wl;
    #pragma unroll
    for (int i = 0; i < 8; ++i) {
        const int j = tid + 256 * i;
        if (rowbase + (j >> 4) < nrows) og[j] = olv[j];
    }
}

// ---------------- CSR build: bucket sort + single finish kernel ----------------
__global__ __launch_bounds__(256) void bucket_hist(const int* __restrict__ dst,
                                                   int* __restrict__ bhist, int nE)
{
    __shared__ int lh[256];
    lh[threadIdx.x] = 0;
    __syncthreads();
    const int stride = gridDim.x * 256;
    for (int e = blockIdx.x * 256 + threadIdx.x; e < nE; e += stride)
        atomicAdd(&lh[dst[e] >> 8], 1);
    __syncthreads();
    const int v = lh[threadIdx.x];
    if (v) atomicAdd(&bhist[threadIdx.x], v);
}

__global__ __launch_bounds__(256) void bucket_scan(const int* __restrict__ bhist,
                                                   int* __restrict__ bstart,
                                                   int* __restrict__ gcursor, int NB, int nE)
{
    __shared__ int s[256];
    const int t = threadIdx.x;
    const int v = (t < NB) ? bhist[t] : 0;
    s[t] = v;
    __syncthreads();
    for (int off = 1; off < 256; off <<= 1) {
        const int tmp = (t >= off) ? s[t - off] : 0;
        __syncthreads();
        s[t] += tmp;
        __syncthreads();
    }
    const int excl = s[t] - v;
    if (t < NB) { bstart[t] = excl; gcursor[t] = excl; }
    if (t == 0) bstart[NB] = nE;
}

__global__ __launch_bounds__(256) void bucket_scatter(const int* __restrict__ src,
                                                      const int* __restrict__ dst,
                                                      int* __restrict__ gcursor,
                                                      uint2* __restrict__ bbuf, int nE)
{
    __shared__ int lh[256], lsc[256], gb[256];
    __shared__ uint2 lbuf[SCHUNK];
    const int tid = threadIdx.x;
    const int base = blockIdx.x * SCHUNK;
    const int cnt = min(SCHUNK, nE - base);
    lh[tid] = 0;
    __syncthreads();
    int b[8], pos[8]; unsigned sv[8], dv[8];
    #pragma unroll
    for (int i = 0; i < 8; ++i) {
        const int li = i * 256 + tid;
        if (li < cnt) {
            sv[i] = src[base + li]; dv[i] = dst[base + li];
            b[i] = dv[i] >> 8;
            pos[i] = atomicAdd(&lh[b[i]], 1);
        } else b[i] = -1;
    }
    __syncthreads();
    const int v = lh[tid];
    lsc[tid] = v;
    __syncthreads();
    for (int off = 1; off < 256; off <<= 1) {
        const int tmp = (tid >= off) ? lsc[tid - off] : 0;
        __syncthreads();
        lsc[tid] += tmp;
        __syncthreads();
    }
    const int excl = lsc[tid] - v;
    __syncthreads();
    lsc[tid] = excl;
    if (v > 0) gb[tid] = atomicAdd(&gcursor[tid], v);
    __syncthreads();
    #pragma unroll
    for (int i = 0; i < 8; ++i)
        if (b[i] >= 0) lbuf[lsc[b[i]] + pos[i]] = make_uint2(sv[i], dv[i]);
    __syncthreads();
    for (int j = tid; j < cnt; j += 256) {
        const uint2 p = lbuf[j];
        const int bb = p.y >> 8;
        bbuf[gb[bb] + (j - lsc[bb])] = p;
    }
}

__global__ __launch_bounds__(256) void bucket_finish(const uint2* __restrict__ bbuf,
                                                     const int* __restrict__ bstart,
                                                     int* __restrict__ start,
                                                     int* __restrict__ csr_src,
                                                     int n, int nE)
{
    __shared__ int lh[256], ns[256], lc[256];
    const int t = threadIdx.x;
    const int b = blockIdx.x;
    lh[t] = 0; lc[t] = 0;
    __syncthreads();
    const int lo = bstart[b], hi = bstart[b + 1];
    for (int j = lo + t; j < hi; j += 256)
        atomicAdd(&lh[bbuf[j].y & 255], 1);
    __syncthreads();
    const int v = lh[t];
    ns[t] = v;
    __syncthreads();
    for (int off = 1; off < 256; off <<= 1) {
        const int tmp = (t >= off) ? ns[t - off] : 0;
        __syncthreads();
        ns[t] += tmp;
        __syncthreads();
    }
    const int excl = ns[t] - v;
    ns[t] = excl + lo;
    const int node = (b << 8) + t;
    if (node < n) start[node] = ns[t];
    if (b == gridDim.x - 1 && t == 0) start[n] = nE;
    __syncthreads();
    for (int j = lo + t; j < hi; j += 256) {
        const uint2 p = bbuf[j];
        const int loc = p.y & 255;
        const int ofs = atomicAdd(&lc[loc], 1);
        csr_src[ns[loc] + ofs] = p.x;
    }
}

// ---------------- pull max (bf16), 4-way ILP ----------------
__global__ __launch_bounds__(256) void pull_max(const ushort* __restrict__ h,
                                                const int* __restrict__ csr_src,
                                                const int* __restrict__ start,
                                                ushort* __restrict__ neigh, int n)
{
    const int lane = threadIdx.x & 63;
    const int wid = threadIdx.x >> 6;
    const int node = blockIdx.x * 4 + wid;
    if (node >= n) return;
    const int s0 = start[node];
    const int s1 = start[node + 1];
    unsigned mlo = 0, mhi = 0;
    for (int base = s0; base < s1; base += 64) {
        const int cnt = min(64, s1 - base);
        const int myidx = (base + lane < s1) ? csr_src[base + lane] : 0;
        int j = 0;
        for (; j + 4 <= cnt; j += 4) {
            const int sa = __shfl(myidx, j, 64);
            const int sb = __shfl(myidx, j + 1, 64);
            const int sc = __shfl(myidx, j + 2, 64);
            const int sd = __shfl(myidx, j + 3, 64);
            const unsigned va = ((const unsigned*)(h + (size_t)sa * DF))[lane];
            const unsigned vb = ((const unsigned*)(h + (size_t)sb * DF))[lane];
            const unsigned vc = ((const unsigned*)(h + (size_t)sc * DF))[lane];
            const unsigned vd = ((const unsigned*)(h + (size_t)sd * DF))[lane];
            mlo = max(mlo, max(max(va & 0xffffu, vb & 0xffffu), max(vc & 0xffffu, vd & 0xffffu)));
            mhi = max(mhi, max(max(va >> 16, vb >> 16), max(vc >> 16, vd >> 16)));
        }
        for (; j < cnt; ++j) {
            const int sa = __shfl(myidx, j, 64);
            const unsigned va = ((const unsigned*)(h + (size_t)sa * DF))[lane];
            mlo = max(mlo, va & 0xffffu);
            mhi = max(mhi, va >> 16);
        }
    }
    ((unsigned*)(neigh + (size_t)node * DF))[lane] = mlo | (mhi << 16);
}

// ---------------- readout ----------------
__global__ __launch_bounds__(128) void colmax(const ushort* __restrict__ x,
                                              unsigned* __restrict__ g, int nrows)
{
    const int c = threadIdx.x;
    float m = 0.f;
    for (int n = blockIdx.x; n < nrows; n += gridDim.x)
        m = fmaxf(m, bf2f(x[(size_t)n * DF + c]));
    atomicMax(g + c, __float_as_uint(m));
}

__global__ __launch_bounds__(128) void head(const float* __restrict__ g,
                                            const float* __restrict__ Wfc1,
                                            const float* __restrict__ bfc1,
                                            const float* __restrict__ Wfc,
                                            const float* __restrict__ bfc,
                                            float* __restrict__ out)
{
    __shared__ float gsh[DF];
    __shared__ float tsh[DF];
    const int t = threadIdx.x;
    gsh[t] = g[t];
    __syncthreads();
    float acc = bfc1[t];
    #pragma unroll 8
    for (int k = 0; k < DF; ++k) acc = fmaf(gsh[k], Wfc1[k * DF + t], acc);
    tsh[t] = acc * Wfc[t];
    __syncthreads();
    if (t == 0) {
        float s = 0.f;
        for (int i = 0; i < DF; ++i) s += tsh[i];
        out[0] = s + bfc[0];
    }
}

extern "C" void kernel_launch(void* const* d_in, const int* in_sizes, int n_in,
                              void* d_out, int out_size, void* d_ws, size_t ws_size,
                              hipStream_t stream) {
    const float* x0     = (const float*)d_in[0];
    const int*   src    = (const int*)d_in[1];
    const int*   dst    = (const int*)d_in[2];
    const float* Wpool0 = (const float*)d_in[3];
    const float* bpool0 = (const float*)d_in[4];
    const float* Wself0 = (const float*)d_in[5];
    const float* Wneigh0= (const float*)d_in[6];
    const float* bias0  = (const float*)d_in[7];
    const float* gamma0 = (const float*)d_in[8];
    const float* beta0  = (const float*)d_in[9];
    const float* Wpool1 = (const float*)d_in[10];
    const float* bpool1 = (const float*)d_in[11];
    const float* Wself1 = (const float*)d_in[12];
    const float* Wneigh1= (const float*)d_in[13];
    const float* bias1  = (const float*)d_in[14];
    const float* gamma1 = (const float*)d_in[15];
    const float* beta1  = (const float*)d_in[16];
    const float* Wfc1   = (const float*)d_in[17];
    const float* bfc1   = (const float*)d_in[18];
    const float* Wfc    = (const float*)d_in[19];
    const float* bfc    = (const float*)d_in[20];

    const int N  = in_sizes[0] / DF;   // 50000
    const int nE = in_sizes[1];        // 800000
    const size_t bufElems = (size_t)N * DF;
    const int NB = (N + 255) >> 8;     // 196 buckets

    ushort* x2b  = (ushort*)d_ws;            // 12.8 MB each
    ushort* x1b  = x2b + bufElems;
    ushort* hb   = x1b + bufElems;
    ushort* nbuf = hb + bufElems;
    uint2* bbuf  = (uint2*)(nbuf + bufElems); // nE pairs = 6.4 MB
    ushort* wfp0 = (ushort*)(bbuf + nE);
    ushort* wfp1 = wfp0 + 16384;
    ushort* wfc0 = wfp1 + 16384;
    ushort* wfc1 = wfc0 + 32768;
    unsigned* g  = (unsigned*)(wfc1 + 32768);
    int* start   = (int*)(g + DF);       // N+1
    int* csr_src = start + N + 1;        // nE
    int* bhist   = csr_src + nE;         // 256
    int* bstart  = bhist + 256;          // 257
    int* gcursor = bstart + 257;         // 256

    const dim3 gP((N + 3) / 4);
    const dim3 gM((N + 127) / 128);      // 391 MFMA-GEMM blocks
    const int nSC = (nE + SCHUNK - 1) / SCHUNK;   // 391

    // ---- prep: all weight fragments + zero bhist/g (1 kernel) ----
    prep_all<<<49, 256, 0, stream>>>(Wpool0, Wpool1, Wself0, Wneigh0, Wself1, Wneigh1,
                                     wfp0, wfp1, wfc0, wfc1, bhist, g);

    // ---- CSR build (bucketed, owner-computes) ----
    bucket_hist<<<256, 256, 0, stream>>>(dst, bhist, nE);
    bucket_scan<<<1, 256, 0, stream>>>(bhist, bstart, gcursor, NB, nE);
    bucket_scatter<<<nSC, 256, 0, stream>>>(src, dst, gcursor, bbuf, nE);
    bucket_finish<<<NB, 256, 0, stream>>>(bbuf, bstart, start, csr_src, N, nE);

    // ---- layer 0 (A-operand direct from fp32 x0) ----
    gemm_pool<1><<<gM, 256, 0, stream>>>(nullptr, x0, wfp0, bpool0, hb, N);
    pull_max<<<gP, 256, 0, stream>>>(hb, csr_src, start, nbuf, N);
    gemm_fused_ln<1><<<gM, 256, 0, stream>>>(nullptr, x0, nbuf, wfc0, bias0, gamma0, beta0, x1b, N);

    // ---- layer 1 ----
    gemm_pool<0><<<gM, 256, 0, stream>>>(x1b, nullptr, wfp1, bpool1, hb, N);
    pull_max<<<gP, 256, 0, stream>>>(hb, csr_src, start, nbuf, N);
    gemm_fused_ln<0><<<gM, 256, 0, stream>>>(x1b, nullptr, nbuf, wfc1, bias1, gamma1, beta1, x2b, N);

    // ---- readout ----
    colmax<<<512, 128, 0, stream>>>(x2b, g, N);
    head<<<1, 128, 0, stream>>>((const float*)g, Wfc1, bfc1, Wfc, bfc, (float*)d_out);
}

// Round 15
// 170.032 us; speedup vs baseline: 8.0333x; 1.1527x over previous
//
#include <hip/hip_runtime.h>

#define DF 128
#define SCHUNK 2048

typedef __attribute__((ext_vector_type(8))) short short8;
typedef __attribute__((ext_vector_type(4))) float f32x4;

__device__ __forceinline__ ushort f2bf(float f) {
    unsigned u = __float_as_uint(f);
    return (ushort)((u + 0x7fffu + ((u >> 16) & 1u)) >> 16);   // RNE
}
__device__ __forceinline__ float bf2f(ushort h) {
    return __uint_as_float(((unsigned)h) << 16);
}
// load 8 fp32, convert to 8 bf16 (RNE) in-register -> MFMA A-fragment
__device__ __forceinline__ short8 ld_a_f32(const float* p) {
    const float4 u = ((const float4*)p)[0];
    const float4 v = ((const float4*)p)[1];
    short8 r;
    r[0] = (short)f2bf(u.x); r[1] = (short)f2bf(u.y);
    r[2] = (short)f2bf(u.z); r[3] = (short)f2bf(u.w);
    r[4] = (short)f2bf(v.x); r[5] = (short)f2bf(v.y);
    r[6] = (short)f2bf(v.z); r[7] = (short)f2bf(v.w);
    return r;
}

// ---------------- prep_all: all 4 weight-fragment buffers + zero bhist/g, one kernel ----------------
__global__ __launch_bounds__(256) void prep_all(const float* __restrict__ Wpool0,
                                                const float* __restrict__ Wpool1,
                                                const float* __restrict__ Wself0,
                                                const float* __restrict__ Wneigh0,
                                                const float* __restrict__ Wself1,
                                                const float* __restrict__ Wneigh1,
                                                ushort* __restrict__ wfp0,
                                                ushort* __restrict__ wfp1,
                                                ushort* __restrict__ wfc0,
                                                ushort* __restrict__ wfc1,
                                                int* __restrict__ bhist,
                                                unsigned* __restrict__ g)
{
    const int tid = threadIdx.x;
    if (blockIdx.x == 48) {
        bhist[tid] = 0;
        if (tid < DF) g[tid] = 0;
        return;
    }
    const int e = blockIdx.x * 256 + tid;
    const float *Wa, *Wb; ushort* out; int le;
    if (e < 2048)      { Wa = Wpool0; Wb = Wpool0;  out = wfp0; le = e; }
    else if (e < 4096) { Wa = Wpool1; Wb = Wpool1;  out = wfp1; le = e - 2048; }
    else if (e < 8192) { Wa = Wself0; Wb = Wneigh0; out = wfc0; le = e - 4096; }
    else               { Wa = Wself1; Wb = Wneigh1; out = wfc1; le = e - 8192; }
    const int kstep = le >> 9;
    const int cb = (le >> 6) & 7;
    const int lane = le & 63;
    const int c = cb * 16 + (lane & 15);
    const int k0 = kstep * 32 + ((lane >> 4) << 3);
    ushort r[8];
    #pragma unroll
    for (int i = 0; i < 8; ++i) {
        const int k = k0 + i;
        const float v = (k < DF) ? Wa[k * DF + c] : Wb[(k - DF) * DF + c];
        r[i] = f2bf(v);
    }
    uint4 o;
    o.x = r[0] | ((unsigned)r[1] << 16);
    o.y = r[2] | ((unsigned)r[3] << 16);
    o.z = r[4] | ((unsigned)r[5] << 16);
    o.w = r[6] | ((unsigned)r[7] << 16);
    ((uint4*)out)[le] = o;
}

// ---------------- MFMA pool GEMM: out = relu(x @ Wpool + b), 128 rows/block ----------------
template<int AF32>
__global__ __launch_bounds__(256) void gemm_pool(const ushort* __restrict__ xb,
                                                 const float* __restrict__ xf,
                                                 const ushort* __restrict__ wf,
                                                 const float* __restrict__ bias,
                                                 ushort* __restrict__ out, int nrows)
{
    __shared__ ushort wl[16384];
    __shared__ float bs[DF];
    const int tid = threadIdx.x;
    {
        const uint4* s = (const uint4*)wf;
        uint4* d = (uint4*)wl;
        #pragma unroll
        for (int i = 0; i < 8; ++i) d[tid + 256 * i] = s[tid + 256 * i];
        if (tid < DF) bs[tid] = bias[tid];
    }
    __syncthreads();

    const int lane = tid & 63;
    const int w = tid >> 6;
    const int rb = blockIdx.x * 128 + w * 32;
    const int ar0 = min(rb + (lane & 15), nrows - 1);
    const int ar1 = min(rb + 16 + (lane & 15), nrows - 1);
    const int ko = (lane >> 4) << 3;

    f32x4 acc[2][8];
    #pragma unroll
    for (int tt = 0; tt < 2; ++tt)
        #pragma unroll
        for (int cb = 0; cb < 8; ++cb) acc[tt][cb] = (f32x4){0.f, 0.f, 0.f, 0.f};

    #pragma unroll
    for (int ks = 0; ks < 4; ++ks) {
        short8 a0, a1;
        if (AF32) {
            a0 = ld_a_f32(xf + (size_t)ar0 * DF + ko + ks * 32);
            a1 = ld_a_f32(xf + (size_t)ar1 * DF + ko + ks * 32);
        } else {
            a0 = *(const short8*)(xb + (size_t)ar0 * DF + ko + ks * 32);
            a1 = *(const short8*)(xb + (size_t)ar1 * DF + ko + ks * 32);
        }
        #pragma unroll
        for (int cb = 0; cb < 8; ++cb) {
            const short8 b = ((const short8*)wl)[(ks * 8 + cb) * 64 + lane];
            acc[0][cb] = __builtin_amdgcn_mfma_f32_16x16x32_bf16(a0, b, acc[0][cb], 0, 0, 0);
            acc[1][cb] = __builtin_amdgcn_mfma_f32_16x16x32_bf16(a1, b, acc[1][cb], 0, 0, 0);
        }
    }
    __syncthreads();   // wl dead as weights; reuse as out staging (32KB)

    ushort* ol = wl;
    #pragma unroll
    for (int tt = 0; tt < 2; ++tt)
        #pragma unroll
        for (int cb = 0; cb < 8; ++cb) {
            const int c = (lane & 15) + (cb << 4);
            const float bv = bs[c];
            #pragma unroll
            for (int reg = 0; reg < 4; ++reg) {
                const int m = ((lane >> 4) << 2) + reg;
                ol[(w * 32 + tt * 16 + m) * DF + c] = f2bf(fmaxf(acc[tt][cb][reg] + bv, 0.f));
            }
        }
    __syncthreads();

    const int rowbase = blockIdx.x * 128;
    uint4* og = (uint4*)(out + (size_t)rowbase * DF);
    const uint4* olv = (const uint4*)wl;
    #pragma unroll
    for (int i = 0; i < 8; ++i) {
        const int j = tid + 256 * i;
        if (rowbase + (j >> 4) < nrows) og[j] = olv[j];
    }
}

// ---------------- MFMA fused GEMM+LN ----------------
// COLMAX=0: write out rows. COLMAX=1: skip global write, column-max -> atomicMax(g).
template<int AF32, int COLMAX>
__global__ __launch_bounds__(256) void gemm_fused_ln(const ushort* __restrict__ xb,
                                                     const float* __restrict__ xf,
                                                     const ushort* __restrict__ nbuf,
                                                     const ushort* __restrict__ wf,
                                                     const float* __restrict__ bias,
                                                     const float* __restrict__ gamma,
                                                     const float* __restrict__ beta,
                                                     ushort* __restrict__ out,
                                                     unsigned* __restrict__ g, int nrows)
{
    __shared__ ushort wl[32768];
    __shared__ float bs[DF], gs[DF], bt[DF];
    __shared__ unsigned cm[DF];
    const int tid = threadIdx.x;
    {
        const uint4* s = (const uint4*)wf;
        uint4* d = (uint4*)wl;
        #pragma unroll
        for (int i = 0; i < 16; ++i) d[tid + 256 * i] = s[tid + 256 * i];
        if (tid < DF) { bs[tid] = bias[tid]; gs[tid] = gamma[tid]; bt[tid] = beta[tid]; }
        if (COLMAX && tid < DF) cm[tid] = 0;
    }
    __syncthreads();

    const int lane = tid & 63;
    const int w = tid >> 6;
    const int rb = blockIdx.x * 128 + w * 32;
    const int ar0 = min(rb + (lane & 15), nrows - 1);
    const int ar1 = min(rb + 16 + (lane & 15), nrows - 1);
    const int ko = (lane >> 4) << 3;
    const ushort* apn0 = nbuf + (size_t)ar0 * DF + ko;
    const ushort* apn1 = nbuf + (size_t)ar1 * DF + ko;

    f32x4 acc[2][8];
    #pragma unroll
    for (int tt = 0; tt < 2; ++tt)
        #pragma unroll
        for (int cb = 0; cb < 8; ++cb) acc[tt][cb] = (f32x4){0.f, 0.f, 0.f, 0.f};

    #pragma unroll
    for (int ks = 0; ks < 8; ++ks) {
        short8 a0, a1;
        if (ks < 4) {
            if (AF32) {
                a0 = ld_a_f32(xf + (size_t)ar0 * DF + ko + ks * 32);
                a1 = ld_a_f32(xf + (size_t)ar1 * DF + ko + ks * 32);
            } else {
                a0 = *(const short8*)(xb + (size_t)ar0 * DF + ko + ks * 32);
                a1 = *(const short8*)(xb + (size_t)ar1 * DF + ko + ks * 32);
            }
        } else {
            a0 = *(const short8*)(apn0 + (ks - 4) * 32);
            a1 = *(const short8*)(apn1 + (ks - 4) * 32);
        }
        #pragma unroll
        for (int cb = 0; cb < 8; ++cb) {
            const short8 b = ((const short8*)wl)[(ks * 8 + cb) * 64 + lane];
            acc[0][cb] = __builtin_amdgcn_mfma_f32_16x16x32_bf16(a0, b, acc[0][cb], 0, 0, 0);
            acc[1][cb] = __builtin_amdgcn_mfma_f32_16x16x32_bf16(a1, b, acc[1][cb], 0, 0, 0);
        }
    }

    float mu[2][4], inv[2][4];
    #pragma unroll
    for (int tt = 0; tt < 2; ++tt) {
        #pragma unroll
        for (int cb = 0; cb < 8; ++cb) {
            const float bv = bs[(lane & 15) + (cb << 4)];
            #pragma unroll
            for (int reg = 0; reg < 4; ++reg) acc[tt][cb][reg] += bv;
        }
        #pragma unroll
        for (int reg = 0; reg < 4; ++reg) {
            float s1 = 0.f, s2 = 0.f;
            #pragma unroll
            for (int cb = 0; cb < 8; ++cb) { const float f = acc[tt][cb][reg]; s1 += f; s2 += f * f; }
            #pragma unroll
            for (int m = 1; m < 16; m <<= 1) { s1 += __shfl_xor(s1, m, 64); s2 += __shfl_xor(s2, m, 64); }
            mu[tt][reg] = s1 * (1.f / 128.f);
            inv[tt][reg] = rsqrtf(s2 * (1.f / 128.f) - mu[tt][reg] * mu[tt][reg] + 1e-5f);
        }
    }
    __syncthreads();   // wl weights dead; reuse as out staging

    ushort* ol = wl;
    #pragma unroll
    for (int tt = 0; tt < 2; ++tt)
        #pragma unroll
        for (int cb = 0; cb < 8; ++cb) {
            const int c = (lane & 15) + (cb << 4);
            const float gv = gs[c], btv = bt[c];
            #pragma unroll
            for (int reg = 0; reg < 4; ++reg) {
                const int m = ((lane >> 4) << 2) + reg;
                const float v = (acc[tt][cb][reg] - mu[tt][reg]) * inv[tt][reg] * gv + btv;
                ol[(w * 32 + tt * 16 + m) * DF + c] = f2bf(fmaxf(v, 0.f));
            }
        }
    __syncthreads();

    if (COLMAX) {
        // per-column max of the 128x128 tile (clamped duplicate rows are harmless for max)
        const int c = tid & 127;
        const int r0 = (tid >> 7) * 64;
        float m = 0.f;
        #pragma unroll 8
        for (int r = r0; r < r0 + 64; ++r)
            m = fmaxf(m, bf2f(ol[r * DF + c]));
        atomicMax(&cm[c], __float_as_uint(m));
        __syncthreads();
        if (tid < DF) atomicMax(g + tid, cm[tid]);
    } else {
        const int rowbase = blockIdx.x * 128;
        uint4* og = (uint4*)(out + (size_t)rowbase * DF);
        const uint4* olv = (const uint4*)wl;
        #pragma unroll
        for (int i = 0; i < 8; ++i) {
            const int j = tid + 256 * i;
            if (rowbase + (j >> 4) < nrows) og[j] = olv[j];
        }
    }
}

// ---------------- CSR build: bucket sort + single finish kernel ----------------
__global__ __launch_bounds__(256) void bucket_hist(const int* __restrict__ dst,
                                                   int* __restrict__ bhist, int nE)
{
    __shared__ int lh[256];
    lh[threadIdx.x] = 0;
    __syncthreads();
    const int stride = gridDim.x * 256;
    for (int e = blockIdx.x * 256 + threadIdx.x; e < nE; e += stride)
        atomicAdd(&lh[dst[e] >> 8], 1);
    __syncthreads();
    const int v = lh[threadIdx.x];
    if (v) atomicAdd(&bhist[threadIdx.x], v);
}

__global__ __launch_bounds__(256) void bucket_scan(const int* __restrict__ bhist,
                                                   int* __restrict__ bstart,
                                                   int* __restrict__ gcursor, int NB, int nE)
{
    __shared__ int s[256];
    const int t = threadIdx.x;
    const int v = (t < NB) ? bhist[t] : 0;
    s[t] = v;
    __syncthreads();
    for (int off = 1; off < 256; off <<= 1) {
        const int tmp = (t >= off) ? s[t - off] : 0;
        __syncthreads();
        s[t] += tmp;
        __syncthreads();
    }
    const int excl = s[t] - v;
    if (t < NB) { bstart[t] = excl; gcursor[t] = excl; }
    if (t == 0) bstart[NB] = nE;
}

__global__ __launch_bounds__(256) void bucket_scatter(const int* __restrict__ src,
                                                      const int* __restrict__ dst,
                                                      int* __restrict__ gcursor,
                                                      uint2* __restrict__ bbuf, int nE)
{
    __shared__ int lh[256], lsc[256], gb[256];
    __shared__ uint2 lbuf[SCHUNK];
    const int tid = threadIdx.x;
    const int base = blockIdx.x * SCHUNK;
    const int cnt = min(SCHUNK, nE - base);
    lh[tid] = 0;
    __syncthreads();
    int b[8], pos[8]; unsigned sv[8], dv[8];
    #pragma unroll
    for (int i = 0; i < 8; ++i) {
        const int li = i * 256 + tid;
        if (li < cnt) {
            sv[i] = src[base + li]; dv[i] = dst[base + li];
            b[i] = dv[i] >> 8;
            pos[i] = atomicAdd(&lh[b[i]], 1);
        } else b[i] = -1;
    }
    __syncthreads();
    const int v = lh[tid];
    lsc[tid] = v;
    __syncthreads();
    for (int off = 1; off < 256; off <<= 1) {
        const int tmp = (tid >= off) ? lsc[tid - off] : 0;
        __syncthreads();
        lsc[tid] += tmp;
        __syncthreads();
    }
    const int excl = lsc[tid] - v;
    __syncthreads();
    lsc[tid] = excl;
    if (v > 0) gb[tid] = atomicAdd(&gcursor[tid], v);
    __syncthreads();
    #pragma unroll
    for (int i = 0; i < 8; ++i)
        if (b[i] >= 0) lbuf[lsc[b[i]] + pos[i]] = make_uint2(sv[i], dv[i]);
    __syncthreads();
    for (int j = tid; j < cnt; j += 256) {
        const uint2 p = lbuf[j];
        const int bb = p.y >> 8;
        bbuf[gb[bb] + (j - lsc[bb])] = p;
    }
}

__global__ __launch_bounds__(256) void bucket_finish(const uint2* __restrict__ bbuf,
                                                     const int* __restrict__ bstart,
                                                     int* __restrict__ start,
                                                     int* __restrict__ csr_src,
                                                     int n, int nE)
{
    __shared__ int lh[256], ns[256], lc[256];
    const int t = threadIdx.x;
    const int b = blockIdx.x;
    lh[t] = 0; lc[t] = 0;
    __syncthreads();
    const int lo = bstart[b], hi = bstart[b + 1];
    for (int j = lo + t; j < hi; j += 256)
        atomicAdd(&lh[bbuf[j].y & 255], 1);
    __syncthreads();
    const int v = lh[t];
    ns[t] = v;
    __syncthreads();
    for (int off = 1; off < 256; off <<= 1) {
        const int tmp = (t >= off) ? ns[t - off] : 0;
        __syncthreads();
        ns[t] += tmp;
        __syncthreads();
    }
    const int excl = ns[t] - v;
    ns[t] = excl + lo;
    const int node = (b << 8) + t;
    if (node < n) start[node] = ns[t];
    if (b == gridDim.x - 1 && t == 0) start[n] = nE;
    __syncthreads();
    for (int j = lo + t; j < hi; j += 256) {
        const uint2 p = bbuf[j];
        const int loc = p.y & 255;
        const int ofs = atomicAdd(&lc[loc], 1);
        csr_src[ns[loc] + ofs] = p.x;
    }
}

// ---------------- pull max (bf16), 4-way ILP ----------------
__global__ __launch_bounds__(256) void pull_max(const ushort* __restrict__ h,
                                                const int* __restrict__ csr_src,
                                                const int* __restrict__ start,
                                                ushort* __restrict__ neigh, int n)
{
    const int lane = threadIdx.x & 63;
    const int wid = threadIdx.x >> 6;
    const int node = blockIdx.x * 4 + wid;
    if (node >= n) return;
    const int s0 = start[node];
    const int s1 = start[node + 1];
    unsigned mlo = 0, mhi = 0;
    for (int base = s0; base < s1; base += 64) {
        const int cnt = min(64, s1 - base);
        const int myidx = (base + lane < s1) ? csr_src[base + lane] : 0;
        int j = 0;
        for (; j + 4 <= cnt; j += 4) {
            const int sa = __shfl(myidx, j, 64);
            const int sb = __shfl(myidx, j + 1, 64);
            const int sc = __shfl(myidx, j + 2, 64);
            const int sd = __shfl(myidx, j + 3, 64);
            const unsigned va = ((const unsigned*)(h + (size_t)sa * DF))[lane];
            const unsigned vb = ((const unsigned*)(h + (size_t)sb * DF))[lane];
            const unsigned vc = ((const unsigned*)(h + (size_t)sc * DF))[lane];
            const unsigned vd = ((const unsigned*)(h + (size_t)sd * DF))[lane];
            mlo = max(mlo, max(max(va & 0xffffu, vb & 0xffffu), max(vc & 0xffffu, vd & 0xffffu)));
            mhi = max(mhi, max(max(va >> 16, vb >> 16), max(vc >> 16, vd >> 16)));
        }
        for (; j < cnt; ++j) {
            const int sa = __shfl(myidx, j, 64);
            const unsigned va = ((const unsigned*)(h + (size_t)sa * DF))[lane];
            mlo = max(mlo, va & 0xffffu);
            mhi = max(mhi, va >> 16);
        }
    }
    ((unsigned*)(neigh + (size_t)node * DF))[lane] = mlo | (mhi << 16);
}

// ---------------- readout head ----------------
__global__ __launch_bounds__(128) void head(const float* __restrict__ g,
                                            const float* __restrict__ Wfc1,
                                            const float* __restrict__ bfc1,
                                            const float* __restrict__ Wfc,
                                            const float* __restrict__ bfc,
                                            float* __restrict__ out)
{
    __shared__ float gsh[DF];
    __shared__ float tsh[DF];
    const int t = threadIdx.x;
    gsh[t] = g[t];
    __syncthreads();
    float acc = bfc1[t];
    #pragma unroll 8
    for (int k = 0; k < DF; ++k) acc = fmaf(gsh[k], Wfc1[k * DF + t], acc);
    tsh[t] = acc * Wfc[t];
    __syncthreads();
    if (t == 0) {
        float s = 0.f;
        for (int i = 0; i < DF; ++i) s += tsh[i];
        out[0] = s + bfc[0];
    }
}

extern "C" void kernel_launch(void* const* d_in, const int* in_sizes, int n_in,
                              void* d_out, int out_size, void* d_ws, size_t ws_size,
                              hipStream_t stream) {
    const float* x0     = (const float*)d_in[0];
    const int*   src    = (const int*)d_in[1];
    const int*   dst    = (const int*)d_in[2];
    const float* Wpool0 = (const float*)d_in[3];
    const float* bpool0 = (const float*)d_in[4];
    const float* Wself0 = (const float*)d_in[5];
    const float* Wneigh0= (const float*)d_in[6];
    const float* bias0  = (const float*)d_in[7];
    const float* gamma0 = (const float*)d_in[8];
    const float* beta0  = (const float*)d_in[9];
    const float* Wpool1 = (const float*)d_in[10];
    const float* bpool1 = (const float*)d_in[11];
    const float* Wself1 = (const float*)d_in[12];
    const float* Wneigh1= (const float*)d_in[13];
    const float* bias1  = (const float*)d_in[14];
    const float* gamma1 = (const float*)d_in[15];
    const float* beta1  = (const float*)d_in[16];
    const float* Wfc1   = (const float*)d_in[17];
    const float* bfc1   = (const float*)d_in[18];
    const float* Wfc    = (const float*)d_in[19];
    const float* bfc    = (const float*)d_in[20];

    const int N  = in_sizes[0] / DF;   // 50000
    const int nE = in_sizes[1];        // 800000
    const size_t bufElems = (size_t)N * DF;
    const int NB = (N + 255) >> 8;     // 196 buckets

    ushort* x1b  = (ushort*)d_ws;            // 12.8 MB each
    ushort* hb   = x1b + bufElems;
    ushort* nbuf = hb + bufElems;
    uint2* bbuf  = (uint2*)(nbuf + bufElems); // nE pairs = 6.4 MB
    ushort* wfp0 = (ushort*)(bbuf + nE);
    ushort* wfp1 = wfp0 + 16384;
    ushort* wfc0 = wfp1 + 16384;
    ushort* wfc1 = wfc0 + 32768;
    unsigned* g  = (unsigned*)(wfc1 + 32768);
    int* start   = (int*)(g + DF);       // N+1
    int* csr_src = start + N + 1;        // nE
    int* bhist   = csr_src + nE;         // 256
    int* bstart  = bhist + 256;          // 257
    int* gcursor = bstart + 257;         // 256

    const dim3 gP((N + 3) / 4);
    const dim3 gM((N + 127) / 128);      // 391 MFMA-GEMM blocks
    const int nSC = (nE + SCHUNK - 1) / SCHUNK;   // 391

    // ---- prep: all weight fragments + zero bhist/g (1 kernel) ----
    prep_all<<<49, 256, 0, stream>>>(Wpool0, Wpool1, Wself0, Wneigh0, Wself1, Wneigh1,
                                     wfp0, wfp1, wfc0, wfc1, bhist, g);

    // ---- CSR build (bucketed, owner-computes) ----
    bucket_hist<<<256, 256, 0, stream>>>(dst, bhist, nE);
    bucket_scan<<<1, 256, 0, stream>>>(bhist, bstart, gcursor, NB, nE);
    bucket_scatter<<<nSC, 256, 0, stream>>>(src, dst, gcursor, bbuf, nE);
    bucket_finish<<<NB, 256, 0, stream>>>(bbuf, bstart, start, csr_src, N, nE);

    // ---- layer 0 (A-operand direct from fp32 x0) ----
    gemm_pool<1><<<gM, 256, 0, stream>>>(nullptr, x0, wfp0, bpool0, hb, N);
    pull_max<<<gP, 256, 0, stream>>>(hb, csr_src, start, nbuf, N);
    gemm_fused_ln<1, 0><<<gM, 256, 0, stream>>>(nullptr, x0, nbuf, wfc0, bias0, gamma0, beta0, x1b, nullptr, N);

    // ---- layer 1 (colmax fused into the final GEMM epilogue) ----
    gemm_pool<0><<<gM, 256, 0, stream>>>(x1b, nullptr, wfp1, bpool1, hb, N);
    pull_max<<<gP, 256, 0, stream>>>(hb, csr_src, start, nbuf, N);
    gemm_fused_ln<0, 1><<<gM, 256, 0, stream>>>(x1b, nullptr, nbuf, wfc1, bias1, gamma1, beta1, nullptr, g, N);

    // ---- readout ----
    head<<<1, 128, 0, stream>>>((const float*)g, Wfc1, bfc1, Wfc, bfc, (float*)d_out);
}